// Round 3
// baseline (515.361 us; speedup 1.0000x reference)
//
#include <hip/hip_runtime.h>
#include <math.h>
#include <stdint.h>

#define B_   4
#define H_   8
#define BH   32
#define T_   8192
#define D_   64
#define NC_  128
#define WSZ_ 64
#define CAND_CAP 512

typedef unsigned short u16;
typedef _Float16 frag8h __attribute__((ext_vector_type(8)));
typedef float floatx4 __attribute__((ext_vector_type(4)));

__device__ inline unsigned pack2h(float a, float b) {
    union { _Float16 h[2]; unsigned u; } p;
    p.h[0] = (_Float16)a; p.h[1] = (_Float16)b;
    return p.u;
}

// ---------------- Kernel A0: fp32 means -> fp16 means + per-cluster |m|^2 ----------------
// 64 blocks x 256 threads; thread handles 4 floats (one quarter of a 16-thread cluster group)
__global__ __launch_bounds__(256) void means16_kernel(
    const float* __restrict__ means, u16* __restrict__ means16, float* __restrict__ msq)
{
    int i = (blockIdx.x * 256 + threadIdx.x) * 4;   // H*NC*D = 65536 floats
    float4 mv = *(const float4*)(means + i);
    uint2 pk = { pack2h(mv.x, mv.y), pack2h(mv.z, mv.w) };
    *(uint2*)&means16[i] = pk;
    // cluster = i/64; 16 consecutive lanes cover one cluster
    float s = mv.x*mv.x + mv.y*mv.y + mv.z*mv.z + mv.w*mv.w;
    s += __shfl_xor(s, 1); s += __shfl_xor(s, 2);
    s += __shfl_xor(s, 4); s += __shfl_xor(s, 8);
    if ((threadIdx.x & 15) == 0) msq[i >> 6] = s;
}

// ---------------- Kernel A v5: global fp16 B-frags, aux via 1-2bv+msq, no spills ----------------
// LDS 17.4 KiB -> 8 blocks/CU; launch_bounds(256,6) caps VGPR at ~85 (kernel needs ~50)
__global__ __launch_bounds__(256, 6) void dist_kernel(
    const float* __restrict__ qg, const float* __restrict__ kg,
    const u16* __restrict__ means16, const float* __restrict__ msq,
    u16* __restrict__ dbuf,
    double* __restrict__ rnorm, double* __restrict__ aux_sum, int pair0)
{
    __shared__ u16 s_ov[128 * 68];       // overlay: xb (64 x stride 72) then C-stage (128 x stride 68)
    __shared__ float s_aux;
    const int tid = threadIdx.x;
    const int bh = pair0 + blockIdx.y;
    const int h  = bh & 7;
    const int tok0 = blockIdx.x * 64;            // within [0, 2T)
    const int isK  = (tok0 >= T_) ? 1 : 0;
    const int tloc0 = isK ? tok0 - T_ : tok0;
    const float* src = isK ? kg : qg;

    if (tid == 0) s_aux = 0.f;
    // token row -> registers; fp64 norm; fp32 normalize; fp16 slice -> xb
    const int row = tid >> 2, sub = tid & 3;
    {
        float xr[16];
        const float* sp = src + ((size_t)bh * T_ + tloc0 + row) * D_ + sub * 16;
        #pragma unroll
        for (int e4 = 0; e4 < 4; e4++) {
            float4 xv = *(const float4*)(sp + e4 * 4);
            xr[e4*4+0] = xv.x; xr[e4*4+1] = xv.y; xr[e4*4+2] = xv.z; xr[e4*4+3] = xv.w;
        }
        double dss = 0.0;
        #pragma unroll
        for (int e = 0; e < 16; e++) { double dv = (double)xr[e]; dss += dv * dv; }
        dss += __shfl_xor(dss, 1); dss += __shfl_xor(dss, 2);
        if (sub == 0) {
            double rn64 = 1.0 / fmax(sqrt(dss), 1e-12);
            rnorm[((size_t)bh * 2 + isK) * T_ + tloc0 + row] = rn64;
        }
        float ss = (float)dss;
        const float rn = 1.0f / fmaxf(sqrtf(ss), 1e-12f);
        #pragma unroll
        for (int e = 0; e < 16; e++) xr[e] *= rn;
        uint4 p0 = { pack2h(xr[0],xr[1]), pack2h(xr[2],xr[3]), pack2h(xr[4],xr[5]), pack2h(xr[6],xr[7]) };
        uint4 p1 = { pack2h(xr[8],xr[9]), pack2h(xr[10],xr[11]), pack2h(xr[12],xr[13]), pack2h(xr[14],xr[15]) };
        *(uint4*)&s_ov[row * 72 + sub * 16]     = p0;
        *(uint4*)&s_ov[row * 72 + sub * 16 + 8] = p1;
    }   // xr dead here -> short live range
    __syncthreads();                               // xb visible
    const int w = tid >> 6, lane = tid & 63;
    const int mrow = lane & 15, quad = lane >> 4;
    const frag8h a0 = *(const frag8h*)&s_ov[(w*16 + mrow)*72 + quad*8];
    const frag8h a1 = *(const frag8h*)&s_ov[(w*16 + mrow)*72 + 32 + quad*8];
    __syncthreads();                               // a-frag reads done before stage overwrite
    {
        const u16* mb = means16 + (size_t)h * (NC_ * D_);
        float bv[4]; int bc[4];
        #pragma unroll
        for (int r = 0; r < 4; r++) { bv[r] = -1e30f; bc[r] = 0; }
        const int tokw = w * 16 + quad * 4;        // block-local token base of my C rows
        #pragma unroll
        for (int n = 0; n < 8; n++) {
            const frag8h b0 = *(const frag8h*)&mb[(n*16 + mrow)*64 + quad*8];
            const frag8h b1 = *(const frag8h*)&mb[(n*16 + mrow)*64 + 32 + quad*8];
            floatx4 acc = {0.f, 0.f, 0.f, 0.f};
            acc = __builtin_amdgcn_mfma_f32_16x16x32_f16(a0, b0, acc, 0, 0, 0);
            acc = __builtin_amdgcn_mfma_f32_16x16x32_f16(a1, b1, acc, 0, 0, 0);
            const int cc = n*16 + mrow;            // cluster (C col = lane&15)
            uint2 pk = { pack2h(acc[0], acc[1]), pack2h(acc[2], acc[3]) };
            *(uint2*)&s_ov[cc * 68 + tokw] = pk;   // stage
            #pragma unroll
            for (int r = 0; r < 4; r++)
                if (acc[r] > bv[r]) { bv[r] = acc[r]; bc[r] = cc; }   // n asc => lowest c on ties
        }
        #pragma unroll
        for (int m = 1; m < 16; m <<= 1) {
            #pragma unroll
            for (int r = 0; r < 4; r++) {
                float ov = __shfl_xor(bv[r], m);
                int   oc = __shfl_xor(bc[r], m);
                if (ov > bv[r] || (ov == bv[r] && oc < bc[r])) { bv[r] = ov; bc[r] = oc; }
            }
        }
        // aux via identity: |x-m|^2 = |x|^2 - 2 x.m + |m|^2 = 1 - 2*bv + msq[c]
        if (mrow == 0) {
            const float* mq = msq + (h << 7);
            float rs = 0.f;
            #pragma unroll
            for (int r = 0; r < 4; r++) rs += 1.0f - 2.0f * bv[r] + mq[bc[r]];
            atomicAdd(&s_aux, rs);
        }
    }
    __syncthreads();                               // stage + s_aux visible
    // coalesced dbuf writeout: 16 lanes cover one 128 B cluster-row segment
    {
        const size_t dbase = ((size_t)blockIdx.y*2 + isK) * NC_;
        #pragma unroll
        for (int it = 0; it < 8; it++) {
            int idx = it * 256 + tid;              // 0..2047
            int crow = idx >> 4;                   // cluster 0..127
            int colg = (idx & 15) * 4;             // token 0..60 step 4
            uint2 pk = *(const uint2*)&s_ov[crow * 68 + colg];
            *(uint2*)&dbuf[(dbase + crow) * T_ + tloc0 + colg] = pk;
        }
    }
    if (tid == 0) atomicAdd(aux_sum, (double)s_aux);
}

// ---------------- Kernel B v4: fp16 keys, 2-bin margin, rnorm-assisted fp64 rank ----------------
__global__ __launch_bounds__(256) void topk_kernel(
    const u16* __restrict__ dbuf, const float* __restrict__ qg,
    const float* __restrict__ kg, const float* __restrict__ means,
    const double* __restrict__ rnorm,
    int* __restrict__ idx_q, int* __restrict__ idx_k, int pair0)
{
    __shared__ int s_hist[2048];          // 4096 logical bins, 2x16-bit packed
    __shared__ int s_scan[256];
    __shared__ int s_wtot[4];
    __shared__ int s_B, s_cnt;
    __shared__ int s_cand[CAND_CAP];
    __shared__ unsigned long long s_key[CAND_CAP];
    __shared__ int s_tok[CAND_CAP];
    __shared__ double s_mean[64];

    const int tid = threadIdx.x;
    const int lane = tid & 63, w = tid >> 6;
    const int c = blockIdx.x, isK = blockIdx.y, pl = blockIdx.z;
    const int bh = pair0 + pl, h = bh & 7;
    const u16* row = dbuf + (((size_t)pl*2 + isK)*NC_ + c)*T_;

    for (int i = tid; i < 2048; i += 256) s_hist[i] = 0;
    if (tid < 64) s_mean[tid] = (double)means[((size_t)h*NC_ + c)*D_ + tid];
    __syncthreads();
    u16 keys[32];
    {
        const uint4* rv = (const uint4*)(row + tid * 32);
        #pragma unroll
        for (int j4 = 0; j4 < 4; j4++) {
            uint4 pk = rv[j4];
            unsigned int wd[4] = {pk.x, pk.y, pk.z, pk.w};
            #pragma unroll
            for (int w2 = 0; w2 < 4; w2++) {
                u16 lo = (u16)(wd[w2] & 0xffffu), hi = (u16)(wd[w2] >> 16);
                keys[j4*8 + w2*2 + 0] = (lo & 0x8000u) ? (u16)(~lo) : (u16)(lo | 0x8000u);
                keys[j4*8 + w2*2 + 1] = (hi & 0x8000u) ? (u16)(~hi) : (u16)(hi | 0x8000u);
            }
        }
    }
    #pragma unroll
    for (int j = 0; j < 32; j++) {
        int b = keys[j] >> 4;
        atomicAdd(&s_hist[b >> 1], 1 << ((b & 1) * 16));
    }
    __syncthreads();
    int cs = 0;
    #pragma unroll
    for (int k2 = 0; k2 < 8; k2++) { int v2 = s_hist[tid*8 + k2]; cs += (v2 & 0xffff) + (v2 >> 16); }
    int sv = cs;
    #pragma unroll
    for (int off = 1; off < 64; off <<= 1) {
        int o = __shfl_down(sv, off);
        if (lane + off < 64) sv += o;
    }
    if (lane == 0) s_wtot[w] = sv;
    __syncthreads();
    {
        int add = 0;
        #pragma unroll
        for (int w2 = 0; w2 < 4; w2++) if (w2 > w) add += s_wtot[w2];
        s_scan[tid] = sv + add;
    }
    __syncthreads();
    {
        int Tj = s_scan[tid];
        int Tn = (tid < 255) ? s_scan[tid + 1] : 0;
        if (Tj >= WSZ_ && Tn < WSZ_) {
            int running = Tn, Bb = tid * 16;
            for (int b2 = tid*16 + 15; b2 >= tid*16; b2--) {
                running += (s_hist[b2 >> 1] >> ((b2 & 1) * 16)) & 0xffff;
                if (running >= WSZ_) { Bb = b2; break; }
            }
            s_B = Bb;
        }
    }
    __syncthreads();
    // fp16 bin = 16 ulp (~0.031 at cutoff); 2-bin margin ~0.062 >> ~1e-3 fp16/MFMA error
    int thr = s_B - 2; if (thr < 0) thr = 0;
    for (;;) {
        if (tid == 0) s_cnt = 0;
        __syncthreads();
        #pragma unroll
        for (int j = 0; j < 32; j++) {
            if ((int)(keys[j] >> 4) >= thr) {
                int p = atomicAdd(&s_cnt, 1);
                if (p < CAND_CAP) s_cand[p] = tid*32 + j;
            }
        }
        __syncthreads();
        if (s_cnt <= CAND_CAP) break;
        thr++;
        __syncthreads();
    }
    const int M = s_cnt;                        // >= 64 by construction
    const float* src = isK ? kg : qg;
    const double* rnrow = rnorm + ((size_t)bh * 2 + isK) * T_;
    {
        const int sub = tid & 3;
        for (int ci = (tid >> 2); ci < M; ci += 64) {
            const int tok = s_cand[ci];
            const float* xr = src + ((size_t)bh*T_ + tok)*D_ + sub*16;
            double dot = 0.0;
            #pragma unroll
            for (int e4 = 0; e4 < 4; e4++) {
                float4 xv4 = *(const float4*)(xr + e4*4);
                const double* mm = &s_mean[sub*16 + e4*4];
                dot += (double)xv4.x*mm[0] + (double)xv4.y*mm[1]
                     + (double)xv4.z*mm[2] + (double)xv4.w*mm[3];
            }
            dot += __shfl_xor(dot, 1); dot += __shfl_xor(dot, 2);
            if (sub == 0) {
                double val = dot * rnrow[tok];
                unsigned long long u = (unsigned long long)__double_as_longlong(val);
                u = (u & 0x8000000000000000ull) ? ~u : (u | 0x8000000000000000ull);
                s_key[ci] = u;
                s_tok[ci] = tok;
            }
        }
    }
    __syncthreads();
    int* dst = (isK ? idx_k : idx_q) + ((size_t)bh*NC_ + c)*WSZ_;
    for (int p = tid; p < M; p += 256) {
        unsigned long long kp = s_key[p];
        int ip = s_tok[p];
        int rank = 0;
        for (int j = 0; j < M; j++) {
            unsigned long long kj = s_key[j];
            int ij = s_tok[j];
            if (kj > kp || (kj == kp && ij < ip)) rank++;
        }
        if (rank < WSZ_) dst[rank] = ip;
    }
}

// ---------------- Kernel C1: selection counts ----------------
__global__ __launch_bounds__(256) void count_kernel(
    const int* __restrict__ idx_q, int* __restrict__ counts)
{
    int i = blockIdx.x * 256 + threadIdx.x;   // 0 .. BH*NC*WSZ-1
    int bh = i >> 13;
    atomicAdd(&counts[bh * T_ + idx_q[i]], 1);
}

// ---------------- Kernel C2: per-bh exclusive scan of counts -> offsets, cursor ----------------
__global__ __launch_bounds__(256) void scan_kernel(
    const int* __restrict__ counts, int* __restrict__ offsets, int* __restrict__ cursor)
{
    __shared__ int s_tmp[256];
    const int tid = threadIdx.x, bh = blockIdx.x;
    const int base = bh * T_;
    int c[32], s = 0;
    #pragma unroll
    for (int j = 0; j < 32; j++) { c[j] = counts[base + tid*32 + j]; s += c[j]; }
    s_tmp[tid] = s;
    __syncthreads();
    for (int off = 1; off < 256; off <<= 1) {
        int add = (tid >= off) ? s_tmp[tid - off] : 0;
        __syncthreads();
        s_tmp[tid] += add;
        __syncthreads();
    }
    int running = s_tmp[tid] - s + bh * (NC_ * WSZ_);   // exclusive prefix + bh base
    #pragma unroll
    for (int j = 0; j < 32; j++) {
        offsets[base + tid*32 + j] = running;
        cursor [base + tid*32 + j] = running;
        running += c[j];
    }
}

// ---------------- Kernel C3: fill CSR entries ----------------
__global__ __launch_bounds__(256) void fill_kernel(
    const int* __restrict__ idx_q, int* __restrict__ cursor, u16* __restrict__ entries)
{
    int i = blockIdx.x * 256 + threadIdx.x;   // 0 .. BH*NC*WSZ-1
    int bh = i >> 13;
    int tok = idx_q[i];
    int pos = atomicAdd(&cursor[bh * T_ + tok], 1);
    entries[pos] = (u16)(i & 8191);           // c*WSZ + slot
}

// ---------------- Kernel D v2: MFMA attention (fp16 QK^T + PV, full softmax) ----------------
__global__ __launch_bounds__(256) void attn_kernel(
    const float* __restrict__ qg, const float* __restrict__ kg, const float* __restrict__ vg,
    const float* __restrict__ mem_k, const float* __restrict__ mem_v,
    const int* __restrict__ idx_q, const int* __restrict__ idx_k,
    float* __restrict__ bo)
{
    __shared__ u16 s_k[80 * 72];    // fp16 K rows [kv][d]: 0=mem, 1..64 gathered, 65..79 zero
    __shared__ u16 s_vt[64 * 72];   // fp16 V^T [d][kv], kv 0..64 valid
    __shared__ int s_qi[WSZ_], s_ki[WSZ_];
    const int tid = threadIdx.x;
    const int c = blockIdx.x, bh = blockIdx.y, h = bh & 7;
    const int lane = tid & 63, w = tid >> 6;
    const int mrow = lane & 15, quad = lane >> 4;

    if (tid < WSZ_) {
        s_qi[tid] = idx_q[((size_t)bh*NC_ + c)*WSZ_ + tid];
        s_ki[tid] = idx_k[((size_t)bh*NC_ + c)*WSZ_ + tid];
    }
    __syncthreads();

    // Q fragments: global -> fp16 regs (row = lane&15 of this wave's 16 q-rows)
    frag8h a0, a1;
    {
        const int qtok = s_qi[w*16 + mrow];
        const float* qr = qg + ((size_t)bh*T_ + qtok)*D_ + quad*8;
        float4 x0 = *(const float4*)(qr);
        float4 x1 = *(const float4*)(qr + 4);
        float4 x2 = *(const float4*)(qr + 32);
        float4 x3 = *(const float4*)(qr + 36);
        a0 = (frag8h){ (_Float16)x0.x,(_Float16)x0.y,(_Float16)x0.z,(_Float16)x0.w,
                       (_Float16)x1.x,(_Float16)x1.y,(_Float16)x1.z,(_Float16)x1.w };
        a1 = (frag8h){ (_Float16)x2.x,(_Float16)x2.y,(_Float16)x2.z,(_Float16)x2.w,
                       (_Float16)x3.x,(_Float16)x3.y,(_Float16)x3.z,(_Float16)x3.w };
    }

    // Stage K rows + V^T cols (80 rows x 4 sub-chunks of 16 dims)
    for (int i = tid; i < 320; i += 256) {
        const int r = i >> 2, sub = i & 3;
        if (r < 65) {
            const float* kp; const float* vp;
            if (r == 0) {
                kp = mem_k + ((size_t)h*NC_ + c)*D_ + sub*16;
                vp = mem_v + ((size_t)h*NC_ + c)*D_ + sub*16;
            } else {
                const int tok = s_ki[r-1];
                kp = kg + ((size_t)bh*T_ + tok)*D_ + sub*16;
                vp = vg + ((size_t)bh*T_ + tok)*D_ + sub*16;
            }
            float kv4[16], vv4[16];
            #pragma unroll
            for (int e4 = 0; e4 < 4; e4++) {
                float4 a = *(const float4*)(kp + e4*4);
                float4 b = *(const float4*)(vp + e4*4);
                kv4[e4*4+0]=a.x; kv4[e4*4+1]=a.y; kv4[e4*4+2]=a.z; kv4[e4*4+3]=a.w;
                vv4[e4*4+0]=b.x; vv4[e4*4+1]=b.y; vv4[e4*4+2]=b.z; vv4[e4*4+3]=b.w;
            }
            uint4 pk0 = { pack2h(kv4[0],kv4[1]),  pack2h(kv4[2],kv4[3]),
                          pack2h(kv4[4],kv4[5]),  pack2h(kv4[6],kv4[7]) };
            uint4 pk1 = { pack2h(kv4[8],kv4[9]),  pack2h(kv4[10],kv4[11]),
                          pack2h(kv4[12],kv4[13]),pack2h(kv4[14],kv4[15]) };
            *(uint4*)&s_k[r*72 + sub*16]     = pk0;
            *(uint4*)&s_k[r*72 + sub*16 + 8] = pk1;
            #pragma unroll
            for (int e = 0; e < 16; e++)
                *(_Float16*)&s_vt[(sub*16 + e)*72 + r] = (_Float16)vv4[e];
        } else {
            uint4 z = {0,0,0,0};
            *(uint4*)&s_k[r*72 + sub*16]     = z;
            *(uint4*)&s_k[r*72 + sub*16 + 8] = z;
        }
    }
    __syncthreads();                 // s_k + s_vt visible

    // QK^T: S[t] holds rows q=quad*4+r, cols kv=t*16+mrow
    floatx4 S[5];
    #pragma unroll
    for (int t = 0; t < 5; t++) {
        const frag8h b0 = *(const frag8h*)&s_k[(t*16 + mrow)*72 + quad*8];
        const frag8h b1 = *(const frag8h*)&s_k[(t*16 + mrow)*72 + 32 + quad*8];
        floatx4 acc = {0.f,0.f,0.f,0.f};
        acc = __builtin_amdgcn_mfma_f32_16x16x32_f16(a0, b0, acc, 0, 0, 0);
        acc = __builtin_amdgcn_mfma_f32_16x16x32_f16(a1, b1, acc, 0, 0, 0);
        S[t] = acc;
    }
    __syncthreads();                 // all waves done reading s_k -> safe to overlay P

    // mask padded kv (tile 4 valid only at kv=64 i.e. mrow==0)
    if (mrow != 0) { S[4][0]=-1e30f; S[4][1]=-1e30f; S[4][2]=-1e30f; S[4][3]=-1e30f; }

    // full softmax per q-row; P (kv 0..63) -> LDS fp16 in A-fragment layout
    float l[4];
    u16* sp = s_k + w * 1152;        // per-wave P [16][72] overlay
    #pragma unroll
    for (int r = 0; r < 4; r++) {
        float m = fmaxf(fmaxf(fmaxf(S[0][r], S[1][r]), fmaxf(S[2][r], S[3][r])), S[4][r]);
        #pragma unroll
        for (int msk = 1; msk < 16; msk <<= 1) m = fmaxf(m, __shfl_xor(m, msk));
        float p16v[5];
        float ps = 0.f;
        #pragma unroll
        for (int t = 0; t < 5; t++) {
            float p = __expf((S[t][r] - m) * 0.125f);
            p16v[t] = (float)(_Float16)p;          // use rounded value consistently
            ps += p16v[t];
        }
        #pragma unroll
        for (int msk = 1; msk < 16; msk <<= 1) ps += __shfl_xor(ps, msk);
        l[r] = ps;
        #pragma unroll
        for (int t = 0; t < 4; t++)
            *(_Float16*)&sp[(quad*4 + r)*72 + t*16 + mrow] = (_Float16)p16v[t];
        S[4][r] = p16v[4];           // stash p(kv=64); valid at mrow==0 lanes
    }

    // PV: O[q][d] = P(16x64) x V(64x..) via MFMA + scalar kv=64 term
    const frag8h pa0 = *(const frag8h*)&sp[mrow*72 + quad*8];
    const frag8h pa1 = *(const frag8h*)&sp[mrow*72 + 32 + quad*8];
    float pm[4];
    #pragma unroll
    for (int r = 0; r < 4; r++) pm[r] = __shfl(S[4][r], lane & 48);
    floatx4 O[4];
    #pragma unroll
    for (int dt = 0; dt < 4; dt++) {
        const frag8h vb0 = *(const frag8h*)&s_vt[(dt*16 + mrow)*72 + quad*8];
        const frag8h vb1 = *(const frag8h*)&s_vt[(dt*16 + mrow)*72 + 32 + quad*8];
        floatx4 acc = {0.f,0.f,0.f,0.f};
        acc = __builtin_amdgcn_mfma_f32_16x16x32_f16(pa0, vb0, acc, 0, 0, 0);
        acc = __builtin_amdgcn_mfma_f32_16x16x32_f16(pa1, vb1, acc, 0, 0, 0);
        const float v64 = (float)*(const _Float16*)&s_vt[(dt*16 + mrow)*72 + 64];
        #pragma unroll
        for (int r = 0; r < 4; r++) acc[r] += pm[r] * v64;
        O[dt] = acc;
    }

    // epilogue: divide by l, store (16-lane coalesced 64 B segments)
    #pragma unroll
    for (int r = 0; r < 4; r++) {
        const float rl = 1.f / l[r];
        float* orow = bo + (((size_t)bh*NC_ + c)*WSZ_ + w*16 + quad*4 + r)*D_ + mrow;
        #pragma unroll
        for (int dt = 0; dt < 4; dt++)
            orow[dt*16] = O[dt][r] * rl;
    }
}

// ---------------- Kernel E: gather + divide + aux ----------------
__global__ __launch_bounds__(256) void gather_kernel(
    const float* __restrict__ bo, const u16* __restrict__ entries,
    const int* __restrict__ offsets, const int* __restrict__ counts,
    const double* __restrict__ aux_sum, float* __restrict__ out)
{
    const int tid = threadIdx.x;
    const int g = blockIdx.x * 4 + (tid >> 6);      // bh*T + tok
    const int lane = tid & 63;
    const int bh = g >> 13;
    const int start = offsets[g];
    const int len = counts[g];
    float sum = 0.f;
    for (int e = 0; e < len; e++) {
        int ent = entries[start + e];
        sum += bo[(((size_t)bh << 13) | (unsigned)ent) * D_ + lane];
    }
    out[(size_t)g * D_ + lane] = sum / ((float)len + 1e-5f);
    if (blockIdx.x == 0 && tid == 0)
        out[(size_t)BH * T_ * D_] = (float)(aux_sum[0] * (0.0001 / 33554432.0));
}

extern "C" void kernel_launch(void* const* d_in, const int* in_sizes, int n_in,
                              void* d_out, int out_size, void* d_ws, size_t ws_size,
                              hipStream_t stream)
{
    const float* q      = (const float*)d_in[0];
    const float* k      = (const float*)d_in[1];
    const float* v      = (const float*)d_in[2];
    const float* means  = (const float*)d_in[3];
    const float* mem_k  = (const float*)d_in[4];
    const float* mem_v  = (const float*)d_in[5];
    float* out = (float*)d_out;

    char* ws = (char*)d_ws;
    const size_t SZ_TOK = (size_t)BH * T_ * sizeof(int);          // 1 MiB
    const size_t SZ_IDX = (size_t)BH * NC_ * WSZ_ * sizeof(int);  // 1 MiB
    size_t off = 256;                                             // [0,256): aux double
    const size_t o_counts  = off; off += SZ_TOK;
    const size_t o_offsets = off; off += SZ_TOK;
    const size_t o_cursor  = off; off += SZ_TOK;
    const size_t o_entries = off; off += (size_t)BH * NC_ * WSZ_ * sizeof(u16);
    const size_t o_idxq    = off; off += SZ_IDX;
    const size_t o_idxk    = off; off += SZ_IDX;
    const size_t o_rnorm   = off; off += (size_t)BH * 2 * T_ * sizeof(double);  // 4 MiB
    const size_t o_m16     = off; off += (size_t)H_ * NC_ * D_ * sizeof(u16);   // 128 KiB
    const size_t o_msq     = off; off += (size_t)H_ * NC_ * sizeof(float);      // 4 KiB
    size_t o_bo = (off + 255) & ~(size_t)255;
    off = o_bo + (size_t)BH * NC_ * WSZ_ * D_ * sizeof(float);    // 64 MiB
    size_t o_dbuf = (off + 255) & ~(size_t)255;

    double* aux   = (double*)ws;
    int* counts   = (int*)(ws + o_counts);
    int* offsets  = (int*)(ws + o_offsets);
    int* cursor   = (int*)(ws + o_cursor);
    u16* entries  = (u16*)(ws + o_entries);
    int* idxq     = (int*)(ws + o_idxq);
    int* idxk     = (int*)(ws + o_idxk);
    double* rnorm = (double*)(ws + o_rnorm);
    u16* m16      = (u16*)(ws + o_m16);
    float* msq    = (float*)(ws + o_msq);
    float* bo     = (float*)(ws + o_bo);
    u16* dbuf     = (u16*)(ws + o_dbuf);

    const size_t per_pair = (size_t)2 * NC_ * T_ * sizeof(u16);   // 4 MiB
    int CH = 32;
    while (CH > 1 && o_dbuf + (size_t)CH * per_pair > ws_size) CH >>= 1;

    hipMemsetAsync(ws, 0, o_offsets, stream);   // zero aux + counts
    means16_kernel<<<dim3(H_ * NC_ * D_ / 1024), 256, 0, stream>>>(means, m16, msq);

    for (int p0 = 0; p0 < BH; p0 += CH) {
        dim3 gA(256, CH);
        dist_kernel<<<gA, 256, 0, stream>>>(q, k, m16, msq, dbuf, rnorm, aux, p0);
        dim3 gB(NC_, 2, CH);
        topk_kernel<<<gB, 256, 0, stream>>>(dbuf, q, k, means, rnorm, idxq, idxk, p0);
    }
    count_kernel<<<dim3(BH * NC_ * WSZ_ / 256), 256, 0, stream>>>(idxq, counts);
    scan_kernel<<<dim3(BH), 256, 0, stream>>>(counts, offsets, cursor);
    fill_kernel<<<dim3(BH * NC_ * WSZ_ / 256), 256, 0, stream>>>(idxq, cursor, entries);
    attn_kernel<<<dim3(NC_, BH), 256, 0, stream>>>(q, k, v, mem_k, mem_v, idxq, idxk, bo);
    gather_kernel<<<dim3(BH * T_ / 4), 256, 0, stream>>>(bo, entries, offsets, counts, aux, out);
}

// Round 5
// 496.010 us; speedup vs baseline: 1.0390x; 1.0390x over previous
//
#include <hip/hip_runtime.h>
#include <math.h>
#include <stdint.h>

#define B_   4
#define H_   8
#define BH   32
#define T_   8192
#define D_   64
#define NC_  128
#define WSZ_ 64
#define CAND_CAP 512

typedef unsigned short u16;
typedef _Float16 frag8h __attribute__((ext_vector_type(8)));
typedef float floatx4 __attribute__((ext_vector_type(4)));

__device__ inline unsigned pack2h(float a, float b) {
    union { _Float16 h[2]; unsigned u; } p;
    p.h[0] = (_Float16)a; p.h[1] = (_Float16)b;
    return p.u;
}

// ---------------- Kernel A0: fp32 means -> fp16 means + per-cluster |m|^2 ----------------
__global__ __launch_bounds__(256) void means16_kernel(
    const float* __restrict__ means, u16* __restrict__ means16, float* __restrict__ msq)
{
    int i = (blockIdx.x * 256 + threadIdx.x) * 4;   // H*NC*D = 65536 floats
    float4 mv = *(const float4*)(means + i);
    uint2 pk = { pack2h(mv.x, mv.y), pack2h(mv.z, mv.w) };
    *(uint2*)&means16[i] = pk;
    // cluster = i/64; 16 consecutive lanes cover one cluster
    float s = mv.x*mv.x + mv.y*mv.y + mv.z*mv.z + mv.w*mv.w;
    s += __shfl_xor(s, 1); s += __shfl_xor(s, 2);
    s += __shfl_xor(s, 4); s += __shfl_xor(s, 8);
    if ((threadIdx.x & 15) == 0) msq[i >> 6] = s;
}

// ---------------- Kernel A v6: B-frags hoisted to registers (16x dwordx4, issued once) ----------------
// LDS 17.4 KiB; VGPR ~96 (b-frags 64 + misc) -> launch_bounds(256,5): 5 blocks/CU, no spill
__global__ __launch_bounds__(256, 5) void dist_kernel(
    const float* __restrict__ qg, const float* __restrict__ kg,
    const u16* __restrict__ means16, const float* __restrict__ msq,
    u16* __restrict__ dbuf,
    double* __restrict__ rnorm, double* __restrict__ aux_sum, int pair0)
{
    __shared__ u16 s_ov[128 * 68];       // overlay: xb (64 x stride 72) then C-stage (128 x stride 68)
    __shared__ float s_aux;
    const int tid = threadIdx.x;
    const int bh = pair0 + blockIdx.y;
    const int h  = bh & 7;
    const int tok0 = blockIdx.x * 64;            // within [0, 2T)
    const int isK  = (tok0 >= T_) ? 1 : 0;
    const int tloc0 = isK ? tok0 - T_ : tok0;
    const float* src = isK ? kg : qg;

    if (tid == 0) s_aux = 0.f;
    // token row -> registers; fp64 norm; fp32 normalize; fp16 slice -> xb
    const int row = tid >> 2, sub = tid & 3;
    {
        float xr[16];
        const float* sp = src + ((size_t)bh * T_ + tloc0 + row) * D_ + sub * 16;
        #pragma unroll
        for (int e4 = 0; e4 < 4; e4++) {
            float4 xv = *(const float4*)(sp + e4 * 4);
            xr[e4*4+0] = xv.x; xr[e4*4+1] = xv.y; xr[e4*4+2] = xv.z; xr[e4*4+3] = xv.w;
        }
        double dss = 0.0;
        #pragma unroll
        for (int e = 0; e < 16; e++) { double dv = (double)xr[e]; dss += dv * dv; }
        dss += __shfl_xor(dss, 1); dss += __shfl_xor(dss, 2);
        if (sub == 0) {
            double rn64 = 1.0 / fmax(sqrt(dss), 1e-12);
            rnorm[((size_t)bh * 2 + isK) * T_ + tloc0 + row] = rn64;
        }
        float ss = (float)dss;
        const float rn = 1.0f / fmaxf(sqrtf(ss), 1e-12f);
        #pragma unroll
        for (int e = 0; e < 16; e++) xr[e] *= rn;
        uint4 p0 = { pack2h(xr[0],xr[1]), pack2h(xr[2],xr[3]), pack2h(xr[4],xr[5]), pack2h(xr[6],xr[7]) };
        uint4 p1 = { pack2h(xr[8],xr[9]), pack2h(xr[10],xr[11]), pack2h(xr[12],xr[13]), pack2h(xr[14],xr[15]) };
        *(uint4*)&s_ov[row * 72 + sub * 16]     = p0;
        *(uint4*)&s_ov[row * 72 + sub * 16 + 8] = p1;
    }   // xr dead -> register headroom for b-frags
    const int w = tid >> 6, lane = tid & 63;
    const int mrow = lane & 15, quad = lane >> 4;
    // hoist ALL B-fragments into registers; 16 independent dwordx4 loads issued
    // back-to-back here, latency hidden under the two barriers + a-frag ds_reads
    frag8h b0[8], b1[8];
    {
        const u16* mb = means16 + (size_t)h * (NC_ * D_);
        #pragma unroll
        for (int n = 0; n < 8; n++) {
            b0[n] = *(const frag8h*)&mb[(n*16 + mrow)*64 + quad*8];
            b1[n] = *(const frag8h*)&mb[(n*16 + mrow)*64 + 32 + quad*8];
        }
    }
    __syncthreads();                               // xb visible
    const frag8h a0 = *(const frag8h*)&s_ov[(w*16 + mrow)*72 + quad*8];
    const frag8h a1 = *(const frag8h*)&s_ov[(w*16 + mrow)*72 + 32 + quad*8];
    __syncthreads();                               // a-frag reads done before stage overwrite
    {
        float bv[4]; int bc[4];
        #pragma unroll
        for (int r = 0; r < 4; r++) { bv[r] = -1e30f; bc[r] = 0; }
        const int tokw = w * 16 + quad * 4;        // block-local token base of my C rows
        #pragma unroll
        for (int n = 0; n < 8; n++) {
            floatx4 acc = {0.f, 0.f, 0.f, 0.f};
            acc = __builtin_amdgcn_mfma_f32_16x16x32_f16(a0, b0[n], acc, 0, 0, 0);
            acc = __builtin_amdgcn_mfma_f32_16x16x32_f16(a1, b1[n], acc, 0, 0, 0);
            const int cc = n*16 + mrow;            // cluster (C col = lane&15)
            uint2 pk = { pack2h(acc[0], acc[1]), pack2h(acc[2], acc[3]) };
            *(uint2*)&s_ov[cc * 68 + tokw] = pk;   // stage
            #pragma unroll
            for (int r = 0; r < 4; r++)
                if (acc[r] > bv[r]) { bv[r] = acc[r]; bc[r] = cc; }   // n asc => lowest c on ties
        }
        #pragma unroll
        for (int m = 1; m < 16; m <<= 1) {
            #pragma unroll
            for (int r = 0; r < 4; r++) {
                float ov = __shfl_xor(bv[r], m);
                int   oc = __shfl_xor(bc[r], m);
                if (ov > bv[r] || (ov == bv[r] && oc < bc[r])) { bv[r] = ov; bc[r] = oc; }
            }
        }
        // aux via identity: |x-m|^2 = |x|^2 - 2 x.m + |m|^2 = 1 - 2*bv + msq[c]
        if (mrow == 0) {
            const float* mq = msq + (h << 7);
            float rs = 0.f;
            #pragma unroll
            for (int r = 0; r < 4; r++) rs += 1.0f - 2.0f * bv[r] + mq[bc[r]];
            atomicAdd(&s_aux, rs);
        }
    }
    __syncthreads();                               // stage + s_aux visible
    // coalesced dbuf writeout: 16 lanes cover one 128 B cluster-row segment
    {
        const size_t dbase = ((size_t)blockIdx.y*2 + isK) * NC_;
        #pragma unroll
        for (int it = 0; it < 8; it++) {
            int idx = it * 256 + tid;              // 0..2047
            int crow = idx >> 4;                   // cluster 0..127
            int colg = (idx & 15) * 4;             // token 0..60 step 4
            uint2 pk = *(const uint2*)&s_ov[crow * 68 + colg];
            *(uint2*)&dbuf[(dbase + crow) * T_ + tloc0 + colg] = pk;
        }
    }
    if (tid == 0) atomicAdd(aux_sum, (double)s_aux);
}

// ---------------- Kernel B v4: fp16 keys, 2-bin margin, rnorm-assisted fp64 rank ----------------
__global__ __launch_bounds__(256) void topk_kernel(
    const u16* __restrict__ dbuf, const float* __restrict__ qg,
    const float* __restrict__ kg, const float* __restrict__ means,
    const double* __restrict__ rnorm,
    int* __restrict__ idx_q, int* __restrict__ idx_k, int pair0)
{
    __shared__ int s_hist[2048];          // 4096 logical bins, 2x16-bit packed
    __shared__ int s_scan[256];
    __shared__ int s_wtot[4];
    __shared__ int s_B, s_cnt;
    __shared__ int s_cand[CAND_CAP];
    __shared__ unsigned long long s_key[CAND_CAP];
    __shared__ int s_tok[CAND_CAP];
    __shared__ double s_mean[64];

    const int tid = threadIdx.x;
    const int lane = tid & 63, w = tid >> 6;
    const int c = blockIdx.x, isK = blockIdx.y, pl = blockIdx.z;
    const int bh = pair0 + pl, h = bh & 7;
    const u16* row = dbuf + (((size_t)pl*2 + isK)*NC_ + c)*T_;

    for (int i = tid; i < 2048; i += 256) s_hist[i] = 0;
    if (tid < 64) s_mean[tid] = (double)means[((size_t)h*NC_ + c)*D_ + tid];
    __syncthreads();
    u16 keys[32];
    {
        const uint4* rv = (const uint4*)(row + tid * 32);
        #pragma unroll
        for (int j4 = 0; j4 < 4; j4++) {
            uint4 pk = rv[j4];
            unsigned int wd[4] = {pk.x, pk.y, pk.z, pk.w};
            #pragma unroll
            for (int w2 = 0; w2 < 4; w2++) {
                u16 lo = (u16)(wd[w2] & 0xffffu), hi = (u16)(wd[w2] >> 16);
                keys[j4*8 + w2*2 + 0] = (lo & 0x8000u) ? (u16)(~lo) : (u16)(lo | 0x8000u);
                keys[j4*8 + w2*2 + 1] = (hi & 0x8000u) ? (u16)(~hi) : (u16)(hi | 0x8000u);
            }
        }
    }
    #pragma unroll
    for (int j = 0; j < 32; j++) {
        int b = keys[j] >> 4;
        atomicAdd(&s_hist[b >> 1], 1 << ((b & 1) * 16));
    }
    __syncthreads();
    int cs = 0;
    #pragma unroll
    for (int k2 = 0; k2 < 8; k2++) { int v2 = s_hist[tid*8 + k2]; cs += (v2 & 0xffff) + (v2 >> 16); }
    int sv = cs;
    #pragma unroll
    for (int off = 1; off < 64; off <<= 1) {
        int o = __shfl_down(sv, off);
        if (lane + off < 64) sv += o;
    }
    if (lane == 0) s_wtot[w] = sv;
    __syncthreads();
    {
        int add = 0;
        #pragma unroll
        for (int w2 = 0; w2 < 4; w2++) if (w2 > w) add += s_wtot[w2];
        s_scan[tid] = sv + add;
    }
    __syncthreads();
    {
        int Tj = s_scan[tid];
        int Tn = (tid < 255) ? s_scan[tid + 1] : 0;
        if (Tj >= WSZ_ && Tn < WSZ_) {
            int running = Tn, Bb = tid * 16;
            for (int b2 = tid*16 + 15; b2 >= tid*16; b2--) {
                running += (s_hist[b2 >> 1] >> ((b2 & 1) * 16)) & 0xffff;
                if (running >= WSZ_) { Bb = b2; break; }
            }
            s_B = Bb;
        }
    }
    __syncthreads();
    // fp16 bin = 16 ulp (~0.031 at cutoff); 2-bin margin ~0.062 >> ~1e-3 fp16/MFMA error
    int thr = s_B - 2; if (thr < 0) thr = 0;
    for (;;) {
        if (tid == 0) s_cnt = 0;
        __syncthreads();
        #pragma unroll
        for (int j = 0; j < 32; j++) {
            if ((int)(keys[j] >> 4) >= thr) {
                int p = atomicAdd(&s_cnt, 1);
                if (p < CAND_CAP) s_cand[p] = tid*32 + j;
            }
        }
        __syncthreads();
        if (s_cnt <= CAND_CAP) break;
        thr++;
        __syncthreads();
    }
    const int M = s_cnt;                        // >= 64 by construction
    const float* src = isK ? kg : qg;
    const double* rnrow = rnorm + ((size_t)bh * 2 + isK) * T_;
    {
        const int sub = tid & 3;
        for (int ci = (tid >> 2); ci < M; ci += 64) {
            const int tok = s_cand[ci];
            const float* xr = src + ((size_t)bh*T_ + tok)*D_ + sub*16;
            double dot = 0.0;
            #pragma unroll
            for (int e4 = 0; e4 < 4; e4++) {
                float4 xv4 = *(const float4*)(xr + e4*4);
                const double* mm = &s_mean[sub*16 + e4*4];
                dot += (double)xv4.x*mm[0] + (double)xv4.y*mm[1]
                     + (double)xv4.z*mm[2] + (double)xv4.w*mm[3];
            }
            dot += __shfl_xor(dot, 1); dot += __shfl_xor(dot, 2);
            if (sub == 0) {
                double val = dot * rnrow[tok];
                unsigned long long u = (unsigned long long)__double_as_longlong(val);
                u = (u & 0x8000000000000000ull) ? ~u : (u | 0x8000000000000000ull);
                s_key[ci] = u;
                s_tok[ci] = tok;
            }
        }
    }
    __syncthreads();
    int* dst = (isK ? idx_k : idx_q) + ((size_t)bh*NC_ + c)*WSZ_;
    for (int p = tid; p < M; p += 256) {
        unsigned long long kp = s_key[p];
        int ip = s_tok[p];
        int rank = 0;
        for (int j = 0; j < M; j++) {
            unsigned long long kj = s_key[j];
            int ij = s_tok[j];
            if (kj > kp || (kj == kp && ij < ip)) rank++;
        }
        if (rank < WSZ_) dst[rank] = ip;
    }
}

// ---------------- Kernel C1: selection counts ----------------
__global__ __launch_bounds__(256) void count_kernel(
    const int* __restrict__ idx_q, int* __restrict__ counts)
{
    int i = blockIdx.x * 256 + threadIdx.x;   // 0 .. BH*NC*WSZ-1
    int bh = i >> 13;
    atomicAdd(&counts[bh * T_ + idx_q[i]], 1);
}

// ---------------- Kernel C2: per-bh exclusive scan of counts -> offsets, cursor ----------------
__global__ __launch_bounds__(256) void scan_kernel(
    const int* __restrict__ counts, int* __restrict__ offsets, int* __restrict__ cursor)
{
    __shared__ int s_tmp[256];
    const int tid = threadIdx.x, bh = blockIdx.x;
    const int base = bh * T_;
    int c[32], s = 0;
    #pragma unroll
    for (int j = 0; j < 32; j++) { c[j] = counts[base + tid*32 + j]; s += c[j]; }
    s_tmp[tid] = s;
    __syncthreads();
    for (int off = 1; off < 256; off <<= 1) {
        int add = (tid >= off) ? s_tmp[tid - off] : 0;
        __syncthreads();
        s_tmp[tid] += add;
        __syncthreads();
    }
    int running = s_tmp[tid] - s + bh * (NC_ * WSZ_);   // exclusive prefix + bh base
    #pragma unroll
    for (int j = 0; j < 32; j++) {
        offsets[base + tid*32 + j] = running;
        cursor [base + tid*32 + j] = running;
        running += c[j];
    }
}

// ---------------- Kernel C3: fill CSR entries ----------------
__global__ __launch_bounds__(256) void fill_kernel(
    const int* __restrict__ idx_q, int* __restrict__ cursor, u16* __restrict__ entries)
{
    int i = blockIdx.x * 256 + threadIdx.x;   // 0 .. BH*NC*WSZ-1
    int bh = i >> 13;
    int tok = idx_q[i];
    int pos = atomicAdd(&cursor[bh * T_ + tok], 1);
    entries[pos] = (u16)(i & 8191);           // c*WSZ + slot
}

// ---------------- Kernel D v2: MFMA attention (fp16 QK^T + PV, full softmax) ----------------
__global__ __launch_bounds__(256) void attn_kernel(
    const float* __restrict__ qg, const float* __restrict__ kg, const float* __restrict__ vg,
    const float* __restrict__ mem_k, const float* __restrict__ mem_v,
    const int* __restrict__ idx_q, const int* __restrict__ idx_k,
    float* __restrict__ bo)
{
    __shared__ u16 s_k[80 * 72];    // fp16 K rows [kv][d]: 0=mem, 1..64 gathered, 65..79 zero
    __shared__ u16 s_vt[64 * 72];   // fp16 V^T [d][kv], kv 0..64 valid
    __shared__ int s_qi[WSZ_], s_ki[WSZ_];
    const int tid = threadIdx.x;
    const int c = blockIdx.x, bh = blockIdx.y, h = bh & 7;
    const int lane = tid & 63, w = tid >> 6;
    const int mrow = lane & 15, quad = lane >> 4;

    if (tid < WSZ_) {
        s_qi[tid] = idx_q[((size_t)bh*NC_ + c)*WSZ_ + tid];
        s_ki[tid] = idx_k[((size_t)bh*NC_ + c)*WSZ_ + tid];
    }
    __syncthreads();

    // Q fragments: global -> fp16 regs (row = lane&15 of this wave's 16 q-rows)
    frag8h a0, a1;
    {
        const int qtok = s_qi[w*16 + mrow];
        const float* qr = qg + ((size_t)bh*T_ + qtok)*D_ + quad*8;
        float4 x0 = *(const float4*)(qr);
        float4 x1 = *(const float4*)(qr + 4);
        float4 x2 = *(const float4*)(qr + 32);
        float4 x3 = *(const float4*)(qr + 36);
        a0 = (frag8h){ (_Float16)x0.x,(_Float16)x0.y,(_Float16)x0.z,(_Float16)x0.w,
                       (_Float16)x1.x,(_Float16)x1.y,(_Float16)x1.z,(_Float16)x1.w };
        a1 = (frag8h){ (_Float16)x2.x,(_Float16)x2.y,(_Float16)x2.z,(_Float16)x2.w,
                       (_Float16)x3.x,(_Float16)x3.y,(_Float16)x3.z,(_Float16)x3.w };
    }

    // Stage K rows + V^T cols (80 rows x 4 sub-chunks of 16 dims)
    for (int i = tid; i < 320; i += 256) {
        const int r = i >> 2, sub = i & 3;
        if (r < 65) {
            const float* kp; const float* vp;
            if (r == 0) {
                kp = mem_k + ((size_t)h*NC_ + c)*D_ + sub*16;
                vp = mem_v + ((size_t)h*NC_ + c)*D_ + sub*16;
            } else {
                const int tok = s_ki[r-1];
                kp = kg + ((size_t)bh*T_ + tok)*D_ + sub*16;
                vp = vg + ((size_t)bh*T_ + tok)*D_ + sub*16;
            }
            float kv4[16], vv4[16];
            #pragma unroll
            for (int e4 = 0; e4 < 4; e4++) {
                float4 a = *(const float4*)(kp + e4*4);
                float4 b = *(const float4*)(vp + e4*4);
                kv4[e4*4+0]=a.x; kv4[e4*4+1]=a.y; kv4[e4*4+2]=a.z; kv4[e4*4+3]=a.w;
                vv4[e4*4+0]=b.x; vv4[e4*4+1]=b.y; vv4[e4*4+2]=b.z; vv4[e4*4+3]=b.w;
            }
            uint4 pk0 = { pack2h(kv4[0],kv4[1]),  pack2h(kv4[2],kv4[3]),
                          pack2h(kv4[4],kv4[5]),  pack2h(kv4[6],kv4[7]) };
            uint4 pk1 = { pack2h(kv4[8],kv4[9]),  pack2h(kv4[10],kv4[11]),
                          pack2h(kv4[12],kv4[13]),pack2h(kv4[14],kv4[15]) };
            *(uint4*)&s_k[r*72 + sub*16]     = pk0;
            *(uint4*)&s_k[r*72 + sub*16 + 8] = pk1;
            #pragma unroll
            for (int e = 0; e < 16; e++)
                *(_Float16*)&s_vt[(sub*16 + e)*72 + r] = (_Float16)vv4[e];
        } else {
            uint4 z = {0,0,0,0};
            *(uint4*)&s_k[r*72 + sub*16]     = z;
            *(uint4*)&s_k[r*72 + sub*16 + 8] = z;
        }
    }
    __syncthreads();                 // s_k + s_vt visible

    // QK^T: S[t] holds rows q=quad*4+r, cols kv=t*16+mrow
    floatx4 S[5];
    #pragma unroll
    for (int t = 0; t < 5; t++) {
        const frag8h b0 = *(const frag8h*)&s_k[(t*16 + mrow)*72 + quad*8];
        const frag8h b1 = *(const frag8h*)&s_k[(t*16 + mrow)*72 + 32 + quad*8];
        floatx4 acc = {0.f,0.f,0.f,0.f};
        acc = __builtin_amdgcn_mfma_f32_16x16x32_f16(a0, b0, acc, 0, 0, 0);
        acc = __builtin_amdgcn_mfma_f32_16x16x32_f16(a1, b1, acc, 0, 0, 0);
        S[t] = acc;
    }
    __syncthreads();                 // all waves done reading s_k -> safe to overlay P

    // mask padded kv (tile 4 valid only at kv=64 i.e. mrow==0)
    if (mrow != 0) { S[4][0]=-1e30f; S[4][1]=-1e30f; S[4][2]=-1e30f; S[4][3]=-1e30f; }

    // full softmax per q-row; P (kv 0..63) -> LDS fp16 in A-fragment layout
    float l[4];
    u16* sp = s_k + w * 1152;        // per-wave P [16][72] overlay
    #pragma unroll
    for (int r = 0; r < 4; r++) {
        float m = fmaxf(fmaxf(fmaxf(S[0][r], S[1][r]), fmaxf(S[2][r], S[3][r])), S[4][r]);
        #pragma unroll
        for (int msk = 1; msk < 16; msk <<= 1) m = fmaxf(m, __shfl_xor(m, msk));
        float p16v[5];
        float ps = 0.f;
        #pragma unroll
        for (int t = 0; t < 5; t++) {
            float p = __expf((S[t][r] - m) * 0.125f);
            p16v[t] = (float)(_Float16)p;          // use rounded value consistently
            ps += p16v[t];
        }
        #pragma unroll
        for (int msk = 1; msk < 16; msk <<= 1) ps += __shfl_xor(ps, msk);
        l[r] = ps;
        #pragma unroll
        for (int t = 0; t < 4; t++)
            *(_Float16*)&sp[(quad*4 + r)*72 + t*16 + mrow] = (_Float16)p16v[t];
        S[4][r] = p16v[4];           // stash p(kv=64); valid at mrow==0 lanes
    }

    // PV: O[q][d] = P(16x64) x V(64x..) via MFMA + scalar kv=64 term
    const frag8h pa0 = *(const frag8h*)&sp[mrow*72 + quad*8];
    const frag8h pa1 = *(const frag8h*)&sp[mrow*72 + 32 + quad*8];
    float pm[4];
    #pragma unroll
    for (int r = 0; r < 4; r++) pm[r] = __shfl(S[4][r], lane & 48);
    floatx4 O[4];
    #pragma unroll
    for (int dt = 0; dt < 4; dt++) {
        const frag8h vb0 = *(const frag8h*)&s_vt[(dt*16 + mrow)*72 + quad*8];
        const frag8h vb1 = *(const frag8h*)&s_vt[(dt*16 + mrow)*72 + 32 + quad*8];
        floatx4 acc = {0.f,0.f,0.f,0.f};
        acc = __builtin_amdgcn_mfma_f32_16x16x32_f16(pa0, vb0, acc, 0, 0, 0);
        acc = __builtin_amdgcn_mfma_f32_16x16x32_f16(pa1, vb1, acc, 0, 0, 0);
        const float v64 = (float)*(const _Float16*)&s_vt[(dt*16 + mrow)*72 + 64];
        #pragma unroll
        for (int r = 0; r < 4; r++) acc[r] += pm[r] * v64;
        O[dt] = acc;
    }

    // epilogue: divide by l, store (16-lane coalesced 64 B segments)
    #pragma unroll
    for (int r = 0; r < 4; r++) {
        const float rl = 1.f / l[r];
        float* orow = bo + (((size_t)bh*NC_ + c)*WSZ_ + w*16 + quad*4 + r)*D_ + mrow;
        #pragma unroll
        for (int dt = 0; dt < 4; dt++)
            orow[dt*16] = O[dt][r] * rl;
    }
}

// ---------------- Kernel E: gather + divide + aux ----------------
__global__ __launch_bounds__(256) void gather_kernel(
    const float* __restrict__ bo, const u16* __restrict__ entries,
    const int* __restrict__ offsets, const int* __restrict__ counts,
    const double* __restrict__ aux_sum, float* __restrict__ out)
{
    const int tid = threadIdx.x;
    const int g = blockIdx.x * 4 + (tid >> 6);      // bh*T + tok
    const int lane = tid & 63;
    const int bh = g >> 13;
    const int start = offsets[g];
    const int len = counts[g];
    float sum = 0.f;
    for (int e = 0; e < len; e++) {
        int ent = entries[start + e];
        sum += bo[(((size_t)bh << 13) | (unsigned)ent) * D_ + lane];
    }
    out[(size_t)g * D_ + lane] = sum / ((float)len + 1e-5f);
    if (blockIdx.x == 0 && tid == 0)
        out[(size_t)BH * T_ * D_] = (float)(aux_sum[0] * (0.0001 / 33554432.0));
}

extern "C" void kernel_launch(void* const* d_in, const int* in_sizes, int n_in,
                              void* d_out, int out_size, void* d_ws, size_t ws_size,
                              hipStream_t stream)
{
    const float* q      = (const float*)d_in[0];
    const float* k      = (const float*)d_in[1];
    const float* v      = (const float*)d_in[2];
    const float* means  = (const float*)d_in[3];
    const float* mem_k  = (const float*)d_in[4];
    const float* mem_v  = (const float*)d_in[5];
    float* out = (float*)d_out;

    char* ws = (char*)d_ws;
    const size_t SZ_TOK = (size_t)BH * T_ * sizeof(int);          // 1 MiB
    const size_t SZ_IDX = (size_t)BH * NC_ * WSZ_ * sizeof(int);  // 1 MiB
    size_t off = 256;                                             // [0,256): aux double
    const size_t o_counts  = off; off += SZ_TOK;
    const size_t o_offsets = off; off += SZ_TOK;
    const size_t o_cursor  = off; off += SZ_TOK;
    const size_t o_entries = off; off += (size_t)BH * NC_ * WSZ_ * sizeof(u16);
    const size_t o_idxq    = off; off += SZ_IDX;
    const size_t o_idxk    = off; off += SZ_IDX;
    const size_t o_rnorm   = off; off += (size_t)BH * 2 * T_ * sizeof(double);  // 4 MiB
    const size_t o_m16     = off; off += (size_t)H_ * NC_ * D_ * sizeof(u16);   // 128 KiB
    const size_t o_msq     = off; off += (size_t)H_ * NC_ * sizeof(float);      // 4 KiB
    size_t o_bo = (off + 255) & ~(size_t)255;
    off = o_bo + (size_t)BH * NC_ * WSZ_ * D_ * sizeof(float);    // 64 MiB
    size_t o_dbuf = (off + 255) & ~(size_t)255;

    double* aux   = (double*)ws;
    int* counts   = (int*)(ws + o_counts);
    int* offsets  = (int*)(ws + o_offsets);
    int* cursor   = (int*)(ws + o_cursor);
    u16* entries  = (u16*)(ws + o_entries);
    int* idxq     = (int*)(ws + o_idxq);
    int* idxk     = (int*)(ws + o_idxk);
    double* rnorm = (double*)(ws + o_rnorm);
    u16* m16      = (u16*)(ws + o_m16);
    float* msq    = (float*)(ws + o_msq);
    float* bo     = (float*)(ws + o_bo);
    u16* dbuf     = (u16*)(ws + o_dbuf);

    const size_t per_pair = (size_t)2 * NC_ * T_ * sizeof(u16);   // 4 MiB
    int CH = 32;
    while (CH > 1 && o_dbuf + (size_t)CH * per_pair > ws_size) CH >>= 1;

    hipMemsetAsync(ws, 0, o_offsets, stream);   // zero aux + counts
    means16_kernel<<<dim3(H_ * NC_ * D_ / 1024), 256, 0, stream>>>(means, m16, msq);

    for (int p0 = 0; p0 < BH; p0 += CH) {
        dim3 gA(256, CH);
        dist_kernel<<<gA, 256, 0, stream>>>(q, k, m16, msq, dbuf, rnorm, aux, p0);
        dim3 gB(NC_, 2, CH);
        topk_kernel<<<gB, 256, 0, stream>>>(dbuf, q, k, means, rnorm, idxq, idxk, p0);
    }
    count_kernel<<<dim3(BH * NC_ * WSZ_ / 256), 256, 0, stream>>>(idxq, counts);
    scan_kernel<<<dim3(BH), 256, 0, stream>>>(counts, offsets, cursor);
    fill_kernel<<<dim3(BH * NC_ * WSZ_ / 256), 256, 0, stream>>>(idxq, cursor, entries);
    attn_kernel<<<dim3(NC_, BH), 256, 0, stream>>>(q, k, v, mem_k, mem_v, idxq, idxk, bo);
    gather_kernel<<<dim3(BH * T_ / 4), 256, 0, stream>>>(bo, entries, offsets, counts, aux, out);
}

// Round 6
// 474.936 us; speedup vs baseline: 1.0851x; 1.0444x over previous
//
#include <hip/hip_runtime.h>
#include <math.h>
#include <stdint.h>

#define B_   4
#define H_   8
#define BH   32
#define T_   8192
#define D_   64
#define NC_  128
#define WSZ_ 64
#define CAND_CAP 512

typedef unsigned short u16;
typedef unsigned char u8;
typedef _Float16 frag8h __attribute__((ext_vector_type(8)));
typedef float floatx4 __attribute__((ext_vector_type(4)));

__device__ inline unsigned pack2h(float a, float b) {
    union { _Float16 h[2]; unsigned u; } p;
    p.h[0] = (_Float16)a; p.h[1] = (_Float16)b;
    return p.u;
}

// ---------------- Kernel A0: fp32 means -> fp16 means + |m|^2 + u8 quant scale ----------------
__global__ __launch_bounds__(256) void means16_kernel(
    const float* __restrict__ means, u16* __restrict__ means16,
    float* __restrict__ msq, float* __restrict__ mscale)
{
    int i = (blockIdx.x * 256 + threadIdx.x) * 4;   // H*NC*D = 65536 floats
    float4 mv = *(const float4*)(means + i);
    uint2 pk = { pack2h(mv.x, mv.y), pack2h(mv.z, mv.w) };
    *(uint2*)&means16[i] = pk;
    // cluster = i/64; 16 consecutive lanes cover one cluster
    float s = mv.x*mv.x + mv.y*mv.y + mv.z*mv.z + mv.w*mv.w;
    s += __shfl_xor(s, 1); s += __shfl_xor(s, 2);
    s += __shfl_xor(s, 4); s += __shfl_xor(s, 8);
    if ((threadIdx.x & 15) == 0) {
        msq[i >> 6] = s;
        mscale[i >> 6] = 127.5f / fmaxf(sqrtf(s), 1e-6f);   // d in [-|m|,|m|] -> [0,255]
    }
}

// ---------------- Kernel A v7: u8 dbuf, slot-spread aux atomic, LDS ~10 KiB ----------------
// dists quantized per-cluster: q = clamp(d*127.5/|m| + 127.5, 0, 255). Bin = |m|/127.5 ~ 0.063
// at cutoff; topk uses 2-bin margin (0.126) >> fp16/MFMA error (~0.02). Exact fp64 rerank after.
__global__ __launch_bounds__(256, 6) void dist_kernel(
    const float* __restrict__ qg, const float* __restrict__ kg,
    const u16* __restrict__ means16, const float* __restrict__ msq,
    const float* __restrict__ mscale,
    u8* __restrict__ dbuf,
    double* __restrict__ rnorm, double* __restrict__ aux_arr, int pair0)
{
    __shared__ u16 s_xb[64 * 72];        // 9216 B; overlaid by u8 stage[128*68]=8704 B after 2nd barrier
    __shared__ float s_sc[128];
    __shared__ float s_aux;
    const int tid = threadIdx.x;
    const int bh = pair0 + blockIdx.y;
    const int h  = bh & 7;
    const int tok0 = blockIdx.x * 64;            // within [0, 2T)
    const int isK  = (tok0 >= T_) ? 1 : 0;
    const int tloc0 = isK ? tok0 - T_ : tok0;
    const float* src = isK ? kg : qg;

    if (tid == 0) s_aux = 0.f;
    if (tid < 128) s_sc[tid] = mscale[(h << 7) + tid];
    // token row -> registers; fp64 norm; fp32 normalize; fp16 slice -> xb
    const int row = tid >> 2, sub = tid & 3;
    {
        float xr[16];
        const float* sp = src + ((size_t)bh * T_ + tloc0 + row) * D_ + sub * 16;
        #pragma unroll
        for (int e4 = 0; e4 < 4; e4++) {
            float4 xv = *(const float4*)(sp + e4 * 4);
            xr[e4*4+0] = xv.x; xr[e4*4+1] = xv.y; xr[e4*4+2] = xv.z; xr[e4*4+3] = xv.w;
        }
        double dss = 0.0;
        #pragma unroll
        for (int e = 0; e < 16; e++) { double dv = (double)xr[e]; dss += dv * dv; }
        dss += __shfl_xor(dss, 1); dss += __shfl_xor(dss, 2);
        if (sub == 0) {
            double rn64 = 1.0 / fmax(sqrt(dss), 1e-12);
            rnorm[((size_t)bh * 2 + isK) * T_ + tloc0 + row] = rn64;
        }
        float ss = (float)dss;
        const float rn = 1.0f / fmaxf(sqrtf(ss), 1e-12f);
        #pragma unroll
        for (int e = 0; e < 16; e++) xr[e] *= rn;
        uint4 p0 = { pack2h(xr[0],xr[1]), pack2h(xr[2],xr[3]), pack2h(xr[4],xr[5]), pack2h(xr[6],xr[7]) };
        uint4 p1 = { pack2h(xr[8],xr[9]), pack2h(xr[10],xr[11]), pack2h(xr[12],xr[13]), pack2h(xr[14],xr[15]) };
        *(uint4*)&s_xb[row * 72 + sub * 16]     = p0;
        *(uint4*)&s_xb[row * 72 + sub * 16 + 8] = p1;
    }   // xr dead -> register headroom for b-frags
    const int w = tid >> 6, lane = tid & 63;
    const int mrow = lane & 15, quad = lane >> 4;
    // hoist B-fragments into registers; independent loads issued back-to-back,
    // latency hidden under the two barriers + a-frag ds_reads
    frag8h b0[8], b1[8];
    {
        const u16* mb = means16 + (size_t)h * (NC_ * D_);
        #pragma unroll
        for (int n = 0; n < 8; n++) {
            b0[n] = *(const frag8h*)&mb[(n*16 + mrow)*64 + quad*8];
            b1[n] = *(const frag8h*)&mb[(n*16 + mrow)*64 + 32 + quad*8];
        }
    }
    __syncthreads();                               // xb + s_sc visible
    const frag8h a0 = *(const frag8h*)&s_xb[(w*16 + mrow)*72 + quad*8];
    const frag8h a1 = *(const frag8h*)&s_xb[(w*16 + mrow)*72 + 32 + quad*8];
    __syncthreads();                               // a-frag reads done before stage overwrite
    u8* st = (u8*)s_xb;                            // u8 stage overlay [128][68]
    {
        float bv[4]; int bc[4];
        #pragma unroll
        for (int r = 0; r < 4; r++) { bv[r] = -1e30f; bc[r] = 0; }
        const int tokw = w * 16 + quad * 4;        // block-local token base of my C rows
        #pragma unroll
        for (int n = 0; n < 8; n++) {
            floatx4 acc = {0.f, 0.f, 0.f, 0.f};
            acc = __builtin_amdgcn_mfma_f32_16x16x32_f16(a0, b0[n], acc, 0, 0, 0);
            acc = __builtin_amdgcn_mfma_f32_16x16x32_f16(a1, b1[n], acc, 0, 0, 0);
            const int cc = n*16 + mrow;            // cluster (C col = lane&15)
            const float sc = s_sc[cc];
            unsigned q0 = (unsigned)(int)fminf(fmaxf(fmaf(acc[0], sc, 127.5f), 0.f), 255.f);
            unsigned q1 = (unsigned)(int)fminf(fmaxf(fmaf(acc[1], sc, 127.5f), 0.f), 255.f);
            unsigned q2 = (unsigned)(int)fminf(fmaxf(fmaf(acc[2], sc, 127.5f), 0.f), 255.f);
            unsigned q3 = (unsigned)(int)fminf(fmaxf(fmaf(acc[3], sc, 127.5f), 0.f), 255.f);
            *(unsigned*)&st[cc * 68 + tokw] = q0 | (q1 << 8) | (q2 << 16) | (q3 << 24);
            #pragma unroll
            for (int r = 0; r < 4; r++)
                if (acc[r] > bv[r]) { bv[r] = acc[r]; bc[r] = cc; }   // n asc => lowest c on ties
        }
        #pragma unroll
        for (int m = 1; m < 16; m <<= 1) {
            #pragma unroll
            for (int r = 0; r < 4; r++) {
                float ov = __shfl_xor(bv[r], m);
                int   oc = __shfl_xor(bc[r], m);
                if (ov > bv[r] || (ov == bv[r] && oc < bc[r])) { bv[r] = ov; bc[r] = oc; }
            }
        }
        // aux via identity: |x-m|^2 = 1 - 2*bv + msq[c]
        if (mrow == 0) {
            const float* mq = msq + (h << 7);
            float rs = 0.f;
            #pragma unroll
            for (int r = 0; r < 4; r++) rs += 1.0f - 2.0f * bv[r] + mq[bc[r]];
            atomicAdd(&s_aux, rs);
        }
    }
    __syncthreads();                               // stage + s_aux visible
    // coalesced dbuf writeout: 16 lanes cover one 64 B cluster-row segment
    {
        const size_t dbase = ((size_t)blockIdx.y*2 + isK) * NC_;
        #pragma unroll
        for (int it = 0; it < 8; it++) {
            int idx = it * 256 + tid;              // 0..2047
            int crow = idx >> 4;                   // cluster 0..127
            int colg = (idx & 15) * 4;             // token 0..60 step 4
            unsigned pk = *(const unsigned*)&st[crow * 68 + colg];
            *(unsigned*)&dbuf[(dbase + crow) * T_ + tloc0 + colg] = pk;
        }
    }
    // slot-spread aux atomic: 64 slots -> same-address contention /64 (Guideline 12)
    if (tid == 0) atomicAdd(&aux_arr[(blockIdx.x ^ blockIdx.y) & 63], (double)s_aux);
}

// ---------------- Kernel B v5: u8 keys, 256-bin histogram, 2-bin margin, fp64 rerank ----------------
__global__ __launch_bounds__(256) void topk_kernel(
    const u8* __restrict__ dbuf, const float* __restrict__ qg,
    const float* __restrict__ kg, const float* __restrict__ means,
    const double* __restrict__ rnorm,
    int* __restrict__ idx_q, int* __restrict__ idx_k, int pair0)
{
    __shared__ int s_hist[128];           // 256 bins, 2x16-bit packed
    __shared__ int s_scan[256];           // reversed prefix = suffix counts
    __shared__ int s_B, s_cnt;
    __shared__ int s_cand[CAND_CAP];
    __shared__ unsigned long long s_key[CAND_CAP];
    __shared__ int s_tok[CAND_CAP];
    __shared__ double s_mean[64];

    const int tid = threadIdx.x;
    const int c = blockIdx.x, isK = blockIdx.y, pl = blockIdx.z;
    const int bh = pair0 + pl, h = bh & 7;
    const u8* row = dbuf + (((size_t)pl*2 + isK)*NC_ + c)*T_;

    if (tid < 128) s_hist[tid] = 0;
    if (tid < 64) s_mean[tid] = (double)means[((size_t)h*NC_ + c)*D_ + tid];
    __syncthreads();
    unsigned wd[8];                        // 32 u8 keys per thread
    {
        const uint4* rv = (const uint4*)(row + tid * 32);
        uint4 a = rv[0], b = rv[1];
        wd[0]=a.x; wd[1]=a.y; wd[2]=a.z; wd[3]=a.w;
        wd[4]=b.x; wd[5]=b.y; wd[6]=b.z; wd[7]=b.w;
    }
    #pragma unroll
    for (int j = 0; j < 32; j++) {
        int b = (wd[j >> 2] >> ((j & 3) * 8)) & 0xff;
        atomicAdd(&s_hist[b >> 1], 1 << ((b & 1) * 16));
    }
    __syncthreads();
    // suffix counts via reversed Hillis-Steele prefix
    {
        int rb = 255 - tid;
        s_scan[tid] = (s_hist[rb >> 1] >> ((rb & 1) * 16)) & 0xffff;
    }
    __syncthreads();
    for (int off = 1; off < 256; off <<= 1) {
        int add = (tid >= off) ? s_scan[tid - off] : 0;
        __syncthreads();
        s_scan[tid] += add;
        __syncthreads();
    }
    {
        int Sb  = s_scan[255 - tid];                       // SUF(tid)
        int Sb1 = (tid < 255) ? s_scan[254 - tid] : 0;     // SUF(tid+1)
        if (Sb >= WSZ_ && Sb1 < WSZ_) s_B = tid;
    }
    __syncthreads();
    int thr = s_B - 2; if (thr < 0) thr = 0;
    for (;;) {
        if (tid == 0) s_cnt = 0;
        __syncthreads();
        #pragma unroll
        for (int j = 0; j < 32; j++) {
            int bv = (wd[j >> 2] >> ((j & 3) * 8)) & 0xff;
            if (bv >= thr) {
                int p = atomicAdd(&s_cnt, 1);
                if (p < CAND_CAP) s_cand[p] = tid*32 + j;
            }
        }
        __syncthreads();
        if (s_cnt <= CAND_CAP) break;
        thr++;
        __syncthreads();
    }
    const int M = s_cnt;                        // >= 64 by construction
    const float* src = isK ? kg : qg;
    const double* rnrow = rnorm + ((size_t)bh * 2 + isK) * T_;
    {
        const int sub = tid & 3;
        for (int ci = (tid >> 2); ci < M; ci += 64) {
            const int tok = s_cand[ci];
            const float* xr = src + ((size_t)bh*T_ + tok)*D_ + sub*16;
            double dot = 0.0;
            #pragma unroll
            for (int e4 = 0; e4 < 4; e4++) {
                float4 xv4 = *(const float4*)(xr + e4*4);
                const double* mm = &s_mean[sub*16 + e4*4];
                dot += (double)xv4.x*mm[0] + (double)xv4.y*mm[1]
                     + (double)xv4.z*mm[2] + (double)xv4.w*mm[3];
            }
            dot += __shfl_xor(dot, 1); dot += __shfl_xor(dot, 2);
            if (sub == 0) {
                double val = dot * rnrow[tok];
                unsigned long long u = (unsigned long long)__double_as_longlong(val);
                u = (u & 0x8000000000000000ull) ? ~u : (u | 0x8000000000000000ull);
                s_key[ci] = u;
                s_tok[ci] = tok;
            }
        }
    }
    __syncthreads();
    int* dst = (isK ? idx_k : idx_q) + ((size_t)bh*NC_ + c)*WSZ_;
    for (int p = tid; p < M; p += 256) {
        unsigned long long kp = s_key[p];
        int ip = s_tok[p];
        int rank = 0;
        for (int j = 0; j < M; j++) {
            unsigned long long kj = s_key[j];
            int ij = s_tok[j];
            if (kj > kp || (kj == kp && ij < ip)) rank++;
        }
        if (rank < WSZ_) dst[rank] = ip;
    }
}

// ---------------- Kernel C1: selection counts ----------------
__global__ __launch_bounds__(256) void count_kernel(
    const int* __restrict__ idx_q, int* __restrict__ counts)
{
    int i = blockIdx.x * 256 + threadIdx.x;   // 0 .. BH*NC*WSZ-1
    int bh = i >> 13;
    atomicAdd(&counts[bh * T_ + idx_q[i]], 1);
}

// ---------------- Kernel C2: per-bh exclusive scan of counts -> offsets, cursor ----------------
__global__ __launch_bounds__(256) void scan_kernel(
    const int* __restrict__ counts, int* __restrict__ offsets, int* __restrict__ cursor)
{
    __shared__ int s_tmp[256];
    const int tid = threadIdx.x, bh = blockIdx.x;
    const int base = bh * T_;
    int c[32], s = 0;
    #pragma unroll
    for (int j = 0; j < 32; j++) { c[j] = counts[base + tid*32 + j]; s += c[j]; }
    s_tmp[tid] = s;
    __syncthreads();
    for (int off = 1; off < 256; off <<= 1) {
        int add = (tid >= off) ? s_tmp[tid - off] : 0;
        __syncthreads();
        s_tmp[tid] += add;
        __syncthreads();
    }
    int running = s_tmp[tid] - s + bh * (NC_ * WSZ_);   // exclusive prefix + bh base
    #pragma unroll
    for (int j = 0; j < 32; j++) {
        offsets[base + tid*32 + j] = running;
        cursor [base + tid*32 + j] = running;
        running += c[j];
    }
}

// ---------------- Kernel C3: fill CSR entries ----------------
__global__ __launch_bounds__(256) void fill_kernel(
    const int* __restrict__ idx_q, int* __restrict__ cursor, u16* __restrict__ entries)
{
    int i = blockIdx.x * 256 + threadIdx.x;   // 0 .. BH*NC*WSZ-1
    int bh = i >> 13;
    int tok = idx_q[i];
    int pos = atomicAdd(&cursor[bh * T_ + tok], 1);
    entries[pos] = (u16)(i & 8191);           // c*WSZ + slot
}

// ---------------- Kernel D v2: MFMA attention (fp16 QK^T + PV, full softmax) ----------------
__global__ __launch_bounds__(256) void attn_kernel(
    const float* __restrict__ qg, const float* __restrict__ kg, const float* __restrict__ vg,
    const float* __restrict__ mem_k, const float* __restrict__ mem_v,
    const int* __restrict__ idx_q, const int* __restrict__ idx_k,
    float* __restrict__ bo)
{
    __shared__ u16 s_k[80 * 72];    // fp16 K rows [kv][d]: 0=mem, 1..64 gathered, 65..79 zero
    __shared__ u16 s_vt[64 * 72];   // fp16 V^T [d][kv], kv 0..64 valid
    __shared__ int s_qi[WSZ_], s_ki[WSZ_];
    const int tid = threadIdx.x;
    const int c = blockIdx.x, bh = blockIdx.y, h = bh & 7;
    const int lane = tid & 63, w = tid >> 6;
    const int mrow = lane & 15, quad = lane >> 4;

    if (tid < WSZ_) {
        s_qi[tid] = idx_q[((size_t)bh*NC_ + c)*WSZ_ + tid];
        s_ki[tid] = idx_k[((size_t)bh*NC_ + c)*WSZ_ + tid];
    }
    __syncthreads();

    // Q fragments: global -> fp16 regs (row = lane&15 of this wave's 16 q-rows)
    frag8h a0, a1;
    {
        const int qtok = s_qi[w*16 + mrow];
        const float* qr = qg + ((size_t)bh*T_ + qtok)*D_ + quad*8;
        float4 x0 = *(const float4*)(qr);
        float4 x1 = *(const float4*)(qr + 4);
        float4 x2 = *(const float4*)(qr + 32);
        float4 x3 = *(const float4*)(qr + 36);
        a0 = (frag8h){ (_Float16)x0.x,(_Float16)x0.y,(_Float16)x0.z,(_Float16)x0.w,
                       (_Float16)x1.x,(_Float16)x1.y,(_Float16)x1.z,(_Float16)x1.w };
        a1 = (frag8h){ (_Float16)x2.x,(_Float16)x2.y,(_Float16)x2.z,(_Float16)x2.w,
                       (_Float16)x3.x,(_Float16)x3.y,(_Float16)x3.z,(_Float16)x3.w };
    }

    // Stage K rows + V^T cols (80 rows x 4 sub-chunks of 16 dims)
    for (int i = tid; i < 320; i += 256) {
        const int r = i >> 2, sub = i & 3;
        if (r < 65) {
            const float* kp; const float* vp;
            if (r == 0) {
                kp = mem_k + ((size_t)h*NC_ + c)*D_ + sub*16;
                vp = mem_v + ((size_t)h*NC_ + c)*D_ + sub*16;
            } else {
                const int tok = s_ki[r-1];
                kp = kg + ((size_t)bh*T_ + tok)*D_ + sub*16;
                vp = vg + ((size_t)bh*T_ + tok)*D_ + sub*16;
            }
            float kv4[16], vv4[16];
            #pragma unroll
            for (int e4 = 0; e4 < 4; e4++) {
                float4 a = *(const float4*)(kp + e4*4);
                float4 b = *(const float4*)(vp + e4*4);
                kv4[e4*4+0]=a.x; kv4[e4*4+1]=a.y; kv4[e4*4+2]=a.z; kv4[e4*4+3]=a.w;
                vv4[e4*4+0]=b.x; vv4[e4*4+1]=b.y; vv4[e4*4+2]=b.z; vv4[e4*4+3]=b.w;
            }
            uint4 pk0 = { pack2h(kv4[0],kv4[1]),  pack2h(kv4[2],kv4[3]),
                          pack2h(kv4[4],kv4[5]),  pack2h(kv4[6],kv4[7]) };
            uint4 pk1 = { pack2h(kv4[8],kv4[9]),  pack2h(kv4[10],kv4[11]),
                          pack2h(kv4[12],kv4[13]),pack2h(kv4[14],kv4[15]) };
            *(uint4*)&s_k[r*72 + sub*16]     = pk0;
            *(uint4*)&s_k[r*72 + sub*16 + 8] = pk1;
            #pragma unroll
            for (int e = 0; e < 16; e++)
                *(_Float16*)&s_vt[(sub*16 + e)*72 + r] = (_Float16)vv4[e];
        } else {
            uint4 z = {0,0,0,0};
            *(uint4*)&s_k[r*72 + sub*16]     = z;
            *(uint4*)&s_k[r*72 + sub*16 + 8] = z;
        }
    }
    __syncthreads();                 // s_k + s_vt visible

    // QK^T: S[t] holds rows q=quad*4+r, cols kv=t*16+mrow
    floatx4 S[5];
    #pragma unroll
    for (int t = 0; t < 5; t++) {
        const frag8h b0 = *(const frag8h*)&s_k[(t*16 + mrow)*72 + quad*8];
        const frag8h b1 = *(const frag8h*)&s_k[(t*16 + mrow)*72 + 32 + quad*8];
        floatx4 acc = {0.f,0.f,0.f,0.f};
        acc = __builtin_amdgcn_mfma_f32_16x16x32_f16(a0, b0, acc, 0, 0, 0);
        acc = __builtin_amdgcn_mfma_f32_16x16x32_f16(a1, b1, acc, 0, 0, 0);
        S[t] = acc;
    }
    __syncthreads();                 // all waves done reading s_k -> safe to overlay P

    // mask padded kv (tile 4 valid only at kv=64 i.e. mrow==0)
    if (mrow != 0) { S[4][0]=-1e30f; S[4][1]=-1e30f; S[4][2]=-1e30f; S[4][3]=-1e30f; }

    // full softmax per q-row; P (kv 0..63) -> LDS fp16 in A-fragment layout
    float l[4];
    u16* sp = s_k + w * 1152;        // per-wave P [16][72] overlay
    #pragma unroll
    for (int r = 0; r < 4; r++) {
        float m = fmaxf(fmaxf(fmaxf(S[0][r], S[1][r]), fmaxf(S[2][r], S[3][r])), S[4][r]);
        #pragma unroll
        for (int msk = 1; msk < 16; msk <<= 1) m = fmaxf(m, __shfl_xor(m, msk));
        float p16v[5];
        float ps = 0.f;
        #pragma unroll
        for (int t = 0; t < 5; t++) {
            float p = __expf((S[t][r] - m) * 0.125f);
            p16v[t] = (float)(_Float16)p;          // use rounded value consistently
            ps += p16v[t];
        }
        #pragma unroll
        for (int msk = 1; msk < 16; msk <<= 1) ps += __shfl_xor(ps, msk);
        l[r] = ps;
        #pragma unroll
        for (int t = 0; t < 4; t++)
            *(_Float16*)&sp[(quad*4 + r)*72 + t*16 + mrow] = (_Float16)p16v[t];
        S[4][r] = p16v[4];           // stash p(kv=64); valid at mrow==0 lanes
    }

    // PV: O[q][d] = P(16x64) x V(64x..) via MFMA + scalar kv=64 term
    const frag8h pa0 = *(const frag8h*)&sp[mrow*72 + quad*8];
    const frag8h pa1 = *(const frag8h*)&sp[mrow*72 + 32 + quad*8];
    float pm[4];
    #pragma unroll
    for (int r = 0; r < 4; r++) pm[r] = __shfl(S[4][r], lane & 48);
    floatx4 O[4];
    #pragma unroll
    for (int dt = 0; dt < 4; dt++) {
        const frag8h vb0 = *(const frag8h*)&s_vt[(dt*16 + mrow)*72 + quad*8];
        const frag8h vb1 = *(const frag8h*)&s_vt[(dt*16 + mrow)*72 + 32 + quad*8];
        floatx4 acc = {0.f,0.f,0.f,0.f};
        acc = __builtin_amdgcn_mfma_f32_16x16x32_f16(pa0, vb0, acc, 0, 0, 0);
        acc = __builtin_amdgcn_mfma_f32_16x16x32_f16(pa1, vb1, acc, 0, 0, 0);
        const float v64 = (float)*(const _Float16*)&s_vt[(dt*16 + mrow)*72 + 64];
        #pragma unroll
        for (int r = 0; r < 4; r++) acc[r] += pm[r] * v64;
        O[dt] = acc;
    }

    // epilogue: divide by l, store (16-lane coalesced 64 B segments)
    #pragma unroll
    for (int r = 0; r < 4; r++) {
        const float rl = 1.f / l[r];
        float* orow = bo + (((size_t)bh*NC_ + c)*WSZ_ + w*16 + quad*4 + r)*D_ + mrow;
        #pragma unroll
        for (int dt = 0; dt < 4; dt++)
            orow[dt*16] = O[dt][r] * rl;
    }
}

// ---------------- Kernel E: gather + divide + aux (64-slot reduce in wave 0 of block 0) ----------------
__global__ __launch_bounds__(256) void gather_kernel(
    const float* __restrict__ bo, const u16* __restrict__ entries,
    const int* __restrict__ offsets, const int* __restrict__ counts,
    const double* __restrict__ aux_arr, float* __restrict__ out)
{
    const int tid = threadIdx.x;
    const int g = blockIdx.x * 4 + (tid >> 6);      // bh*T + tok
    const int lane = tid & 63;
    const int bh = g >> 13;
    const int start = offsets[g];
    const int len = counts[g];
    float sum = 0.f;
    for (int e = 0; e < len; e++) {
        int ent = entries[start + e];
        sum += bo[(((size_t)bh << 13) | (unsigned)ent) * D_ + lane];
    }
    out[(size_t)g * D_ + lane] = sum / ((float)len + 1e-5f);
    if (blockIdx.x == 0 && tid < 64) {
        double v = aux_arr[tid];
        #pragma unroll
        for (int m = 1; m < 64; m <<= 1) v += __shfl_xor(v, m);
        if (tid == 0)
            out[(size_t)BH * T_ * D_] = (float)(v * (0.0001 / 33554432.0));
    }
}

extern "C" void kernel_launch(void* const* d_in, const int* in_sizes, int n_in,
                              void* d_out, int out_size, void* d_ws, size_t ws_size,
                              hipStream_t stream)
{
    const float* q      = (const float*)d_in[0];
    const float* k      = (const float*)d_in[1];
    const float* v      = (const float*)d_in[2];
    const float* means  = (const float*)d_in[3];
    const float* mem_k  = (const float*)d_in[4];
    const float* mem_v  = (const float*)d_in[5];
    float* out = (float*)d_out;

    char* ws = (char*)d_ws;
    const size_t SZ_TOK = (size_t)BH * T_ * sizeof(int);          // 1 MiB
    const size_t SZ_IDX = (size_t)BH * NC_ * WSZ_ * sizeof(int);  // 1 MiB
    size_t off = 512;                                             // [0,512): aux_arr 64 doubles
    const size_t o_counts  = off; off += SZ_TOK;
    const size_t o_offsets = off; off += SZ_TOK;
    const size_t o_cursor  = off; off += SZ_TOK;
    const size_t o_entries = off; off += (size_t)BH * NC_ * WSZ_ * sizeof(u16);
    const size_t o_idxq    = off; off += SZ_IDX;
    const size_t o_idxk    = off; off += SZ_IDX;
    const size_t o_rnorm   = off; off += (size_t)BH * 2 * T_ * sizeof(double);  // 4 MiB
    const size_t o_m16     = off; off += (size_t)H_ * NC_ * D_ * sizeof(u16);   // 128 KiB
    const size_t o_msq     = off; off += (size_t)H_ * NC_ * sizeof(float);      // 4 KiB
    const size_t o_mscale  = off; off += (size_t)H_ * NC_ * sizeof(float);      // 4 KiB
    size_t o_bo = (off + 255) & ~(size_t)255;
    off = o_bo + (size_t)BH * NC_ * WSZ_ * D_ * sizeof(float);    // 64 MiB
    size_t o_dbuf = (off + 255) & ~(size_t)255;

    double* aux   = (double*)ws;
    int* counts   = (int*)(ws + o_counts);
    int* offsets  = (int*)(ws + o_offsets);
    int* cursor   = (int*)(ws + o_cursor);
    u16* entries  = (u16*)(ws + o_entries);
    int* idxq     = (int*)(ws + o_idxq);
    int* idxk     = (int*)(ws + o_idxk);
    double* rnorm = (double*)(ws + o_rnorm);
    u16* m16      = (u16*)(ws + o_m16);
    float* msq    = (float*)(ws + o_msq);
    float* mscale = (float*)(ws + o_mscale);
    float* bo     = (float*)(ws + o_bo);
    u8* dbuf      = (u8*)(ws + o_dbuf);

    const size_t per_pair = (size_t)2 * NC_ * T_ * sizeof(u8);    // 2 MiB
    int CH = 32;
    while (CH > 1 && o_dbuf + (size_t)CH * per_pair > ws_size) CH >>= 1;

    hipMemsetAsync(ws, 0, o_offsets, stream);   // zero aux + counts
    means16_kernel<<<dim3(H_ * NC_ * D_ / 1024), 256, 0, stream>>>(means, m16, msq, mscale);

    for (int p0 = 0; p0 < BH; p0 += CH) {
        dim3 gA(256, CH);
        dist_kernel<<<gA, 256, 0, stream>>>(q, k, m16, msq, mscale, dbuf, rnorm, aux, p0);
        dim3 gB(NC_, 2, CH);
        topk_kernel<<<gB, 256, 0, stream>>>(dbuf, q, k, means, rnorm, idxq, idxk, p0);
    }
    count_kernel<<<dim3(BH * NC_ * WSZ_ / 256), 256, 0, stream>>>(idxq, counts);
    scan_kernel<<<dim3(BH), 256, 0, stream>>>(counts, offsets, cursor);
    fill_kernel<<<dim3(BH * NC_ * WSZ_ / 256), 256, 0, stream>>>(idxq, cursor, entries);
    attn_kernel<<<dim3(NC_, BH), 256, 0, stream>>>(q, k, v, mem_k, mem_v, idxq, idxk, bo);
    gather_kernel<<<dim3(BH * T_ / 4), 256, 0, stream>>>(bo, entries, offsets, counts, aux, out);
}

// Round 7
// 441.830 us; speedup vs baseline: 1.1664x; 1.0749x over previous
//
#include <hip/hip_runtime.h>
#include <math.h>
#include <stdint.h>

#define B_   4
#define H_   8
#define BH   32
#define T_   8192
#define D_   64
#define NC_  128
#define WSZ_ 64
#define CAND_CAP 512

typedef unsigned short u16;
typedef unsigned char u8;
typedef _Float16 frag8h __attribute__((ext_vector_type(8)));
typedef float floatx4 __attribute__((ext_vector_type(4)));

__device__ inline unsigned pack2h(float a, float b) {
    union { _Float16 h[2]; unsigned u; } p;
    p.h[0] = (_Float16)a; p.h[1] = (_Float16)b;
    return p.u;
}

// ---------------- Kernel A0: fp32 means -> fp16 means + |m|^2 + u8 quant scale ----------------
__global__ __launch_bounds__(256) void means16_kernel(
    const float* __restrict__ means, u16* __restrict__ means16,
    float* __restrict__ msq, float* __restrict__ mscale)
{
    int i = (blockIdx.x * 256 + threadIdx.x) * 4;   // H*NC*D = 65536 floats
    float4 mv = *(const float4*)(means + i);
    uint2 pk = { pack2h(mv.x, mv.y), pack2h(mv.z, mv.w) };
    *(uint2*)&means16[i] = pk;
    // cluster = i/64; 16 consecutive lanes cover one cluster
    float s = mv.x*mv.x + mv.y*mv.y + mv.z*mv.z + mv.w*mv.w;
    s += __shfl_xor(s, 1); s += __shfl_xor(s, 2);
    s += __shfl_xor(s, 4); s += __shfl_xor(s, 8);
    if ((threadIdx.x & 15) == 0) {
        msq[i >> 6] = s;
        mscale[i >> 6] = 127.5f / fmaxf(sqrtf(s), 1e-6f);   // d in [-|m|,|m|] -> [0,255]
    }
}

// ---------------- Kernel A v8: 512 thr / 128 tokens, LDS-staged fp16 means, u8 dbuf ----------------
// MFMA loop reads B-frags via ds_read_b128 (~12cy) instead of L2 (~200cy, r3-r6 mistake).
// LDS: s_mb 18.4K + s_xb 18.4K (u8 stage overlay 16.9K) + misc = 37.4K -> 4 blk/CU = 32 waves (100%)
__global__ __launch_bounds__(512, 6) void dist_kernel(
    const float* __restrict__ qg, const float* __restrict__ kg,
    const u16* __restrict__ means16, const float* __restrict__ msq,
    const float* __restrict__ mscale,
    u8* __restrict__ dbuf,
    double* __restrict__ rnorm, double* __restrict__ aux_arr, int pair0)
{
    __shared__ u16 s_mb[128 * 72];       // fp16 means, stride 72
    __shared__ u16 s_xb[128 * 72];       // fp16 tokens; overlaid by u8 stage [128][132] after 2nd barrier
    __shared__ float s_sc[128];
    __shared__ float s_aux;
    const int tid = threadIdx.x;
    const int bh = pair0 + blockIdx.y;
    const int h  = bh & 7;
    const int tok0 = blockIdx.x * 128;           // within [0, 2T)
    const int isK  = (tok0 >= T_) ? 1 : 0;
    const int tloc0 = isK ? tok0 - T_ : tok0;
    const float* src = isK ? kg : qg;

    if (tid == 0) s_aux = 0.f;
    if (tid < 128) s_sc[tid] = mscale[(h << 7) + tid];
    // means16 (u16 global, L2-hot) -> LDS: 8192 u16, 16/thread
    {
        const u16* mh = means16 + (size_t)h * (NC_ * D_);
        #pragma unroll
        for (int it = 0; it < 2; it++) {
            int i = (it * 512 + tid) * 8;          // u16 index
            uint4 mv = *(const uint4*)(mh + i);
            *(uint4*)&s_mb[(i >> 6) * 72 + (i & 63)] = mv;
        }
    }
    // token row -> registers; fp64 norm; fp32 normalize; fp16 slice -> xb
    const int row = tid >> 2, sub = tid & 3;      // row 0..127
    {
        float xr[16];
        const float* sp = src + ((size_t)bh * T_ + tloc0 + row) * D_ + sub * 16;
        #pragma unroll
        for (int e4 = 0; e4 < 4; e4++) {
            float4 xv = *(const float4*)(sp + e4 * 4);
            xr[e4*4+0] = xv.x; xr[e4*4+1] = xv.y; xr[e4*4+2] = xv.z; xr[e4*4+3] = xv.w;
        }
        double dss = 0.0;
        #pragma unroll
        for (int e = 0; e < 16; e++) { double dv = (double)xr[e]; dss += dv * dv; }
        dss += __shfl_xor(dss, 1); dss += __shfl_xor(dss, 2);
        if (sub == 0) {
            double rn64 = 1.0 / fmax(sqrt(dss), 1e-12);
            rnorm[((size_t)bh * 2 + isK) * T_ + tloc0 + row] = rn64;
        }
        float ss = (float)dss;
        const float rn = 1.0f / fmaxf(sqrtf(ss), 1e-12f);
        #pragma unroll
        for (int e = 0; e < 16; e++) xr[e] *= rn;
        uint4 p0 = { pack2h(xr[0],xr[1]), pack2h(xr[2],xr[3]), pack2h(xr[4],xr[5]), pack2h(xr[6],xr[7]) };
        uint4 p1 = { pack2h(xr[8],xr[9]), pack2h(xr[10],xr[11]), pack2h(xr[12],xr[13]), pack2h(xr[14],xr[15]) };
        *(uint4*)&s_xb[row * 72 + sub * 16]     = p0;
        *(uint4*)&s_xb[row * 72 + sub * 16 + 8] = p1;
    }
    __syncthreads();                               // mb + xb + s_sc visible
    const int w = tid >> 6, lane = tid & 63;       // w 0..7 -> 16-token tile per wave
    const int mrow = lane & 15, quad = lane >> 4;
    const frag8h a0 = *(const frag8h*)&s_xb[(w*16 + mrow)*72 + quad*8];
    const frag8h a1 = *(const frag8h*)&s_xb[(w*16 + mrow)*72 + 32 + quad*8];
    __syncthreads();                               // a-frag reads done before stage overwrite
    u8* st = (u8*)s_xb;                            // u8 stage overlay [128][132]
    {
        float bv[4]; int bc[4];
        #pragma unroll
        for (int r = 0; r < 4; r++) { bv[r] = -1e30f; bc[r] = 0; }
        const int tokw = w * 16 + quad * 4;        // block-local token base 0..124
        #pragma unroll
        for (int n = 0; n < 8; n++) {
            const frag8h b0 = *(const frag8h*)&s_mb[(n*16 + mrow)*72 + quad*8];
            const frag8h b1 = *(const frag8h*)&s_mb[(n*16 + mrow)*72 + 32 + quad*8];
            floatx4 acc = {0.f, 0.f, 0.f, 0.f};
            acc = __builtin_amdgcn_mfma_f32_16x16x32_f16(a0, b0, acc, 0, 0, 0);
            acc = __builtin_amdgcn_mfma_f32_16x16x32_f16(a1, b1, acc, 0, 0, 0);
            const int cc = n*16 + mrow;            // cluster (C col = lane&15)
            const float sc = s_sc[cc];
            unsigned q0 = (unsigned)(int)fminf(fmaxf(fmaf(acc[0], sc, 127.5f), 0.f), 255.f);
            unsigned q1 = (unsigned)(int)fminf(fmaxf(fmaf(acc[1], sc, 127.5f), 0.f), 255.f);
            unsigned q2 = (unsigned)(int)fminf(fmaxf(fmaf(acc[2], sc, 127.5f), 0.f), 255.f);
            unsigned q3 = (unsigned)(int)fminf(fmaxf(fmaf(acc[3], sc, 127.5f), 0.f), 255.f);
            *(unsigned*)&st[cc * 132 + tokw] = q0 | (q1 << 8) | (q2 << 16) | (q3 << 24);
            #pragma unroll
            for (int r = 0; r < 4; r++)
                if (acc[r] > bv[r]) { bv[r] = acc[r]; bc[r] = cc; }   // n asc => lowest c on ties
        }
        #pragma unroll
        for (int m = 1; m < 16; m <<= 1) {
            #pragma unroll
            for (int r = 0; r < 4; r++) {
                float ov = __shfl_xor(bv[r], m);
                int   oc = __shfl_xor(bc[r], m);
                if (ov > bv[r] || (ov == bv[r] && oc < bc[r])) { bv[r] = ov; bc[r] = oc; }
            }
        }
        // aux via identity: |x-m|^2 = 1 - 2*bv + msq[c]
        if (mrow == 0) {
            const float* mq = msq + (h << 7);
            float rs = 0.f;
            #pragma unroll
            for (int r = 0; r < 4; r++) rs += 1.0f - 2.0f * bv[r] + mq[bc[r]];
            atomicAdd(&s_aux, rs);
        }
    }
    __syncthreads();                               // stage + s_aux visible
    // coalesced dbuf writeout: 32 lanes cover one 128 B cluster-row segment
    {
        const size_t dbase = ((size_t)blockIdx.y*2 + isK) * NC_;
        #pragma unroll
        for (int it = 0; it < 8; it++) {
            int idx = it * 512 + tid;              // 0..4095
            int crow = idx >> 5;                   // cluster 0..127
            int colg = (idx & 31) * 4;             // token 0..124 step 4
            unsigned pk = *(const unsigned*)&st[crow * 132 + colg];
            *(unsigned*)&dbuf[(dbase + crow) * T_ + tloc0 + colg] = pk;
        }
    }
    // slot-spread aux atomic (Guideline 12)
    if (tid == 0) atomicAdd(&aux_arr[(blockIdx.x ^ blockIdx.y) & 63], (double)s_aux);
}

// ---------------- Kernel B v5: u8 keys, 256-bin histogram, 2-bin margin, fp64 rerank ----------------
__global__ __launch_bounds__(256) void topk_kernel(
    const u8* __restrict__ dbuf, const float* __restrict__ qg,
    const float* __restrict__ kg, const float* __restrict__ means,
    const double* __restrict__ rnorm,
    int* __restrict__ idx_q, int* __restrict__ idx_k, int pair0)
{
    __shared__ int s_hist[128];           // 256 bins, 2x16-bit packed
    __shared__ int s_scan[256];           // reversed prefix = suffix counts
    __shared__ int s_B, s_cnt;
    __shared__ int s_cand[CAND_CAP];
    __shared__ unsigned long long s_key[CAND_CAP];
    __shared__ int s_tok[CAND_CAP];
    __shared__ double s_mean[64];

    const int tid = threadIdx.x;
    const int c = blockIdx.x, isK = blockIdx.y, pl = blockIdx.z;
    const int bh = pair0 + pl, h = bh & 7;
    const u8* row = dbuf + (((size_t)pl*2 + isK)*NC_ + c)*T_;

    if (tid < 128) s_hist[tid] = 0;
    if (tid < 64) s_mean[tid] = (double)means[((size_t)h*NC_ + c)*D_ + tid];
    __syncthreads();
    unsigned wd[8];                        // 32 u8 keys per thread
    {
        const uint4* rv = (const uint4*)(row + tid * 32);
        uint4 a = rv[0], b = rv[1];
        wd[0]=a.x; wd[1]=a.y; wd[2]=a.z; wd[3]=a.w;
        wd[4]=b.x; wd[5]=b.y; wd[6]=b.z; wd[7]=b.w;
    }
    #pragma unroll
    for (int j = 0; j < 32; j++) {
        int b = (wd[j >> 2] >> ((j & 3) * 8)) & 0xff;
        atomicAdd(&s_hist[b >> 1], 1 << ((b & 1) * 16));
    }
    __syncthreads();
    // suffix counts via reversed Hillis-Steele prefix
    {
        int rb = 255 - tid;
        s_scan[tid] = (s_hist[rb >> 1] >> ((rb & 1) * 16)) & 0xffff;
    }
    __syncthreads();
    for (int off = 1; off < 256; off <<= 1) {
        int add = (tid >= off) ? s_scan[tid - off] : 0;
        __syncthreads();
        s_scan[tid] += add;
        __syncthreads();
    }
    {
        int Sb  = s_scan[255 - tid];                       // SUF(tid)
        int Sb1 = (tid < 255) ? s_scan[254 - tid] : 0;     // SUF(tid+1)
        if (Sb >= WSZ_ && Sb1 < WSZ_) s_B = tid;
    }
    __syncthreads();
    int thr = s_B - 2; if (thr < 0) thr = 0;
    for (;;) {
        if (tid == 0) s_cnt = 0;
        __syncthreads();
        #pragma unroll
        for (int j = 0; j < 32; j++) {
            int bv = (wd[j >> 2] >> ((j & 3) * 8)) & 0xff;
            if (bv >= thr) {
                int p = atomicAdd(&s_cnt, 1);
                if (p < CAND_CAP) s_cand[p] = tid*32 + j;
            }
        }
        __syncthreads();
        if (s_cnt <= CAND_CAP) break;
        thr++;
        __syncthreads();
    }
    const int M = s_cnt;                        // >= 64 by construction
    const float* src = isK ? kg : qg;
    const double* rnrow = rnorm + ((size_t)bh * 2 + isK) * T_;
    {
        const int sub = tid & 3;
        for (int ci = (tid >> 2); ci < M; ci += 64) {
            const int tok = s_cand[ci];
            const float* xr = src + ((size_t)bh*T_ + tok)*D_ + sub*16;
            double dot = 0.0;
            #pragma unroll
            for (int e4 = 0; e4 < 4; e4++) {
                float4 xv4 = *(const float4*)(xr + e4*4);
                const double* mm = &s_mean[sub*16 + e4*4];
                dot += (double)xv4.x*mm[0] + (double)xv4.y*mm[1]
                     + (double)xv4.z*mm[2] + (double)xv4.w*mm[3];
            }
            dot += __shfl_xor(dot, 1); dot += __shfl_xor(dot, 2);
            if (sub == 0) {
                double val = dot * rnrow[tok];
                unsigned long long u = (unsigned long long)__double_as_longlong(val);
                u = (u & 0x8000000000000000ull) ? ~u : (u | 0x8000000000000000ull);
                s_key[ci] = u;
                s_tok[ci] = tok;
            }
        }
    }
    __syncthreads();
    int* dst = (isK ? idx_k : idx_q) + ((size_t)bh*NC_ + c)*WSZ_;
    for (int p = tid; p < M; p += 256) {
        unsigned long long kp = s_key[p];
        int ip = s_tok[p];
        int rank = 0;
        for (int j = 0; j < M; j++) {
            unsigned long long kj = s_key[j];
            int ij = s_tok[j];
            if (kj > kp || (kj == kp && ij < ip)) rank++;
        }
        if (rank < WSZ_) dst[rank] = ip;
    }
}

// ---------------- Kernel C1: selection counts ----------------
__global__ __launch_bounds__(256) void count_kernel(
    const int* __restrict__ idx_q, int* __restrict__ counts)
{
    int i = blockIdx.x * 256 + threadIdx.x;   // 0 .. BH*NC*WSZ-1
    int bh = i >> 13;
    atomicAdd(&counts[bh * T_ + idx_q[i]], 1);
}

// ---------------- Kernel C2: per-bh exclusive scan of counts -> offsets, cursor ----------------
__global__ __launch_bounds__(256) void scan_kernel(
    const int* __restrict__ counts, int* __restrict__ offsets, int* __restrict__ cursor)
{
    __shared__ int s_tmp[256];
    const int tid = threadIdx.x, bh = blockIdx.x;
    const int base = bh * T_;
    int c[32], s = 0;
    #pragma unroll
    for (int j = 0; j < 32; j++) { c[j] = counts[base + tid*32 + j]; s += c[j]; }
    s_tmp[tid] = s;
    __syncthreads();
    for (int off = 1; off < 256; off <<= 1) {
        int add = (tid >= off) ? s_tmp[tid - off] : 0;
        __syncthreads();
        s_tmp[tid] += add;
        __syncthreads();
    }
    int running = s_tmp[tid] - s + bh * (NC_ * WSZ_);   // exclusive prefix + bh base
    #pragma unroll
    for (int j = 0; j < 32; j++) {
        offsets[base + tid*32 + j] = running;
        cursor [base + tid*32 + j] = running;
        running += c[j];
    }
}

// ---------------- Kernel C3: fill CSR entries ----------------
__global__ __launch_bounds__(256) void fill_kernel(
    const int* __restrict__ idx_q, int* __restrict__ cursor, u16* __restrict__ entries)
{
    int i = blockIdx.x * 256 + threadIdx.x;   // 0 .. BH*NC*WSZ-1
    int bh = i >> 13;
    int tok = idx_q[i];
    int pos = atomicAdd(&cursor[bh * T_ + tok], 1);
    entries[pos] = (u16)(i & 8191);           // c*WSZ + slot
}

// ---------------- Kernel D v2: MFMA attention (fp16 QK^T + PV, full softmax) ----------------
__global__ __launch_bounds__(256) void attn_kernel(
    const float* __restrict__ qg, const float* __restrict__ kg, const float* __restrict__ vg,
    const float* __restrict__ mem_k, const float* __restrict__ mem_v,
    const int* __restrict__ idx_q, const int* __restrict__ idx_k,
    float* __restrict__ bo)
{
    __shared__ u16 s_k[80 * 72];    // fp16 K rows [kv][d]: 0=mem, 1..64 gathered, 65..79 zero
    __shared__ u16 s_vt[64 * 72];   // fp16 V^T [d][kv], kv 0..64 valid
    __shared__ int s_qi[WSZ_], s_ki[WSZ_];
    const int tid = threadIdx.x;
    const int c = blockIdx.x, bh = blockIdx.y, h = bh & 7;
    const int lane = tid & 63, w = tid >> 6;
    const int mrow = lane & 15, quad = lane >> 4;

    if (tid < WSZ_) {
        s_qi[tid] = idx_q[((size_t)bh*NC_ + c)*WSZ_ + tid];
        s_ki[tid] = idx_k[((size_t)bh*NC_ + c)*WSZ_ + tid];
    }
    __syncthreads();

    // Q fragments: global -> fp16 regs (row = lane&15 of this wave's 16 q-rows)
    frag8h a0, a1;
    {
        const int qtok = s_qi[w*16 + mrow];
        const float* qr = qg + ((size_t)bh*T_ + qtok)*D_ + quad*8;
        float4 x0 = *(const float4*)(qr);
        float4 x1 = *(const float4*)(qr + 4);
        float4 x2 = *(const float4*)(qr + 32);
        float4 x3 = *(const float4*)(qr + 36);
        a0 = (frag8h){ (_Float16)x0.x,(_Float16)x0.y,(_Float16)x0.z,(_Float16)x0.w,
                       (_Float16)x1.x,(_Float16)x1.y,(_Float16)x1.z,(_Float16)x1.w };
        a1 = (frag8h){ (_Float16)x2.x,(_Float16)x2.y,(_Float16)x2.z,(_Float16)x2.w,
                       (_Float16)x3.x,(_Float16)x3.y,(_Float16)x3.z,(_Float16)x3.w };
    }

    // Stage K rows + V^T cols (80 rows x 4 sub-chunks of 16 dims)
    for (int i = tid; i < 320; i += 256) {
        const int r = i >> 2, sub = i & 3;
        if (r < 65) {
            const float* kp; const float* vp;
            if (r == 0) {
                kp = mem_k + ((size_t)h*NC_ + c)*D_ + sub*16;
                vp = mem_v + ((size_t)h*NC_ + c)*D_ + sub*16;
            } else {
                const int tok = s_ki[r-1];
                kp = kg + ((size_t)bh*T_ + tok)*D_ + sub*16;
                vp = vg + ((size_t)bh*T_ + tok)*D_ + sub*16;
            }
            float kv4[16], vv4[16];
            #pragma unroll
            for (int e4 = 0; e4 < 4; e4++) {
                float4 a = *(const float4*)(kp + e4*4);
                float4 b = *(const float4*)(vp + e4*4);
                kv4[e4*4+0]=a.x; kv4[e4*4+1]=a.y; kv4[e4*4+2]=a.z; kv4[e4*4+3]=a.w;
                vv4[e4*4+0]=b.x; vv4[e4*4+1]=b.y; vv4[e4*4+2]=b.z; vv4[e4*4+3]=b.w;
            }
            uint4 pk0 = { pack2h(kv4[0],kv4[1]),  pack2h(kv4[2],kv4[3]),
                          pack2h(kv4[4],kv4[5]),  pack2h(kv4[6],kv4[7]) };
            uint4 pk1 = { pack2h(kv4[8],kv4[9]),  pack2h(kv4[10],kv4[11]),
                          pack2h(kv4[12],kv4[13]),pack2h(kv4[14],kv4[15]) };
            *(uint4*)&s_k[r*72 + sub*16]     = pk0;
            *(uint4*)&s_k[r*72 + sub*16 + 8] = pk1;
            #pragma unroll
            for (int e = 0; e < 16; e++)
                *(_Float16*)&s_vt[(sub*16 + e)*72 + r] = (_Float16)vv4[e];
        } else {
            uint4 z = {0,0,0,0};
            *(uint4*)&s_k[r*72 + sub*16]     = z;
            *(uint4*)&s_k[r*72 + sub*16 + 8] = z;
        }
    }
    __syncthreads();                 // s_k + s_vt visible

    // QK^T: S[t] holds rows q=quad*4+r, cols kv=t*16+mrow
    floatx4 S[5];
    #pragma unroll
    for (int t = 0; t < 5; t++) {
        const frag8h b0 = *(const frag8h*)&s_k[(t*16 + mrow)*72 + quad*8];
        const frag8h b1 = *(const frag8h*)&s_k[(t*16 + mrow)*72 + 32 + quad*8];
        floatx4 acc = {0.f,0.f,0.f,0.f};
        acc = __builtin_amdgcn_mfma_f32_16x16x32_f16(a0, b0, acc, 0, 0, 0);
        acc = __builtin_amdgcn_mfma_f32_16x16x32_f16(a1, b1, acc, 0, 0, 0);
        S[t] = acc;
    }
    __syncthreads();                 // all waves done reading s_k -> safe to overlay P

    // mask padded kv (tile 4 valid only at kv=64 i.e. mrow==0)
    if (mrow != 0) { S[4][0]=-1e30f; S[4][1]=-1e30f; S[4][2]=-1e30f; S[4][3]=-1e30f; }

    // full softmax per q-row; P (kv 0..63) -> LDS fp16 in A-fragment layout
    float l[4];
    u16* sp = s_k + w * 1152;        // per-wave P [16][72] overlay
    #pragma unroll
    for (int r = 0; r < 4; r++) {
        float m = fmaxf(fmaxf(fmaxf(S[0][r], S[1][r]), fmaxf(S[2][r], S[3][r])), S[4][r]);
        #pragma unroll
        for (int msk = 1; msk < 16; msk <<= 1) m = fmaxf(m, __shfl_xor(m, msk));
        float p16v[5];
        float ps = 0.f;
        #pragma unroll
        for (int t = 0; t < 5; t++) {
            float p = __expf((S[t][r] - m) * 0.125f);
            p16v[t] = (float)(_Float16)p;          // use rounded value consistently
            ps += p16v[t];
        }
        #pragma unroll
        for (int msk = 1; msk < 16; msk <<= 1) ps += __shfl_xor(ps, msk);
        l[r] = ps;
        #pragma unroll
        for (int t = 0; t < 4; t++)
            *(_Float16*)&sp[(quad*4 + r)*72 + t*16 + mrow] = (_Float16)p16v[t];
        S[4][r] = p16v[4];           // stash p(kv=64); valid at mrow==0 lanes
    }

    // PV: O[q][d] = P(16x64) x V(64x..) via MFMA + scalar kv=64 term
    const frag8h pa0 = *(const frag8h*)&sp[mrow*72 + quad*8];
    const frag8h pa1 = *(const frag8h*)&sp[mrow*72 + 32 + quad*8];
    float pm[4];
    #pragma unroll
    for (int r = 0; r < 4; r++) pm[r] = __shfl(S[4][r], lane & 48);
    floatx4 O[4];
    #pragma unroll
    for (int dt = 0; dt < 4; dt++) {
        const frag8h vb0 = *(const frag8h*)&s_vt[(dt*16 + mrow)*72 + quad*8];
        const frag8h vb1 = *(const frag8h*)&s_vt[(dt*16 + mrow)*72 + 32 + quad*8];
        floatx4 acc = {0.f,0.f,0.f,0.f};
        acc = __builtin_amdgcn_mfma_f32_16x16x32_f16(pa0, vb0, acc, 0, 0, 0);
        acc = __builtin_amdgcn_mfma_f32_16x16x32_f16(pa1, vb1, acc, 0, 0, 0);
        const float v64 = (float)*(const _Float16*)&s_vt[(dt*16 + mrow)*72 + 64];
        #pragma unroll
        for (int r = 0; r < 4; r++) acc[r] += pm[r] * v64;
        O[dt] = acc;
    }

    // epilogue: divide by l, store (16-lane coalesced 64 B segments)
    #pragma unroll
    for (int r = 0; r < 4; r++) {
        const float rl = 1.f / l[r];
        float* orow = bo + (((size_t)bh*NC_ + c)*WSZ_ + w*16 + quad*4 + r)*D_ + mrow;
        #pragma unroll
        for (int dt = 0; dt < 4; dt++)
            orow[dt*16] = O[dt][r] * rl;
    }
}

// ---------------- Kernel E: gather + divide + aux (64-slot reduce in wave 0 of block 0) ----------------
__global__ __launch_bounds__(256) void gather_kernel(
    const float* __restrict__ bo, const u16* __restrict__ entries,
    const int* __restrict__ offsets, const int* __restrict__ counts,
    const double* __restrict__ aux_arr, float* __restrict__ out)
{
    const int tid = threadIdx.x;
    const int g = blockIdx.x * 4 + (tid >> 6);      // bh*T + tok
    const int lane = tid & 63;
    const int bh = g >> 13;
    const int start = offsets[g];
    const int len = counts[g];
    float sum = 0.f;
    for (int e = 0; e < len; e++) {
        int ent = entries[start + e];
        sum += bo[(((size_t)bh << 13) | (unsigned)ent) * D_ + lane];
    }
    out[(size_t)g * D_ + lane] = sum / ((float)len + 1e-5f);
    if (blockIdx.x == 0 && tid < 64) {
        double v = aux_arr[tid];
        #pragma unroll
        for (int m = 1; m < 64; m <<= 1) v += __shfl_xor(v, m);
        if (tid == 0)
            out[(size_t)BH * T_ * D_] = (float)(v * (0.0001 / 33554432.0));
    }
}

extern "C" void kernel_launch(void* const* d_in, const int* in_sizes, int n_in,
                              void* d_out, int out_size, void* d_ws, size_t ws_size,
                              hipStream_t stream)
{
    const float* q      = (const float*)d_in[0];
    const float* k      = (const float*)d_in[1];
    const float* v      = (const float*)d_in[2];
    const float* means  = (const float*)d_in[3];
    const float* mem_k  = (const float*)d_in[4];
    const float* mem_v  = (const float*)d_in[5];
    float* out = (float*)d_out;

    char* ws = (char*)d_ws;
    const size_t SZ_TOK = (size_t)BH * T_ * sizeof(int);          // 1 MiB
    const size_t SZ_IDX = (size_t)BH * NC_ * WSZ_ * sizeof(int);  // 1 MiB
    size_t off = 512;                                             // [0,512): aux_arr 64 doubles
    const size_t o_counts  = off; off += SZ_TOK;
    const size_t o_offsets = off; off += SZ_TOK;
    const size_t o_cursor  = off; off += SZ_TOK;
    const size_t o_entries = off; off += (size_t)BH * NC_ * WSZ_ * sizeof(u16);
    const size_t o_idxq    = off; off += SZ_IDX;
    const size_t o_idxk    = off; off += SZ_IDX;
    const size_t o_rnorm   = off; off += (size_t)BH * 2 * T_ * sizeof(double);  // 4 MiB
    const size_t o_m16     = off; off += (size_t)H_ * NC_ * D_ * sizeof(u16);   // 128 KiB
    const size_t o_msq     = off; off += (size_t)H_ * NC_ * sizeof(float);      // 4 KiB
    const size_t o_mscale  = off; off += (size_t)H_ * NC_ * sizeof(float);      // 4 KiB
    size_t o_bo = (off + 255) & ~(size_t)255;
    off = o_bo + (size_t)BH * NC_ * WSZ_ * D_ * sizeof(float);    // 64 MiB
    size_t o_dbuf = (off + 255) & ~(size_t)255;

    double* aux   = (double*)ws;
    int* counts   = (int*)(ws + o_counts);
    int* offsets  = (int*)(ws + o_offsets);
    int* cursor   = (int*)(ws + o_cursor);
    u16* entries  = (u16*)(ws + o_entries);
    int* idxq     = (int*)(ws + o_idxq);
    int* idxk     = (int*)(ws + o_idxk);
    double* rnorm = (double*)(ws + o_rnorm);
    u16* m16      = (u16*)(ws + o_m16);
    float* msq    = (float*)(ws + o_msq);
    float* mscale = (float*)(ws + o_mscale);
    float* bo     = (float*)(ws + o_bo);
    u8* dbuf      = (u8*)(ws + o_dbuf);

    const size_t per_pair = (size_t)2 * NC_ * T_ * sizeof(u8);    // 2 MiB
    int CH = 32;
    while (CH > 1 && o_dbuf + (size_t)CH * per_pair > ws_size) CH >>= 1;

    hipMemsetAsync(ws, 0, o_offsets, stream);   // zero aux + counts
    means16_kernel<<<dim3(H_ * NC_ * D_ / 1024), 256, 0, stream>>>(means, m16, msq, mscale);

    for (int p0 = 0; p0 < BH; p0 += CH) {
        dim3 gA(128, CH);
        dist_kernel<<<gA, 512, 0, stream>>>(q, k, m16, msq, mscale, dbuf, rnorm, aux, p0);
        dim3 gB(NC_, 2, CH);
        topk_kernel<<<gB, 256, 0, stream>>>(dbuf, q, k, means, rnorm, idxq, idxk, p0);
    }
    count_kernel<<<dim3(BH * NC_ * WSZ_ / 256), 256, 0, stream>>>(idxq, counts);
    scan_kernel<<<dim3(BH), 256, 0, stream>>>(counts, offsets, cursor);
    fill_kernel<<<dim3(BH * NC_ * WSZ_ / 256), 256, 0, stream>>>(idxq, cursor, entries);
    attn_kernel<<<dim3(NC_, BH), 256, 0, stream>>>(q, k, v, mem_k, mem_v, idxq, idxk, bo);
    gather_kernel<<<dim3(BH * T_ / 4), 256, 0, stream>>>(bo, entries, offsets, counts, aux, out);
}